// Round 1
// baseline (13160.370 us; speedup 1.0000x reference)
//
#include <hip/hip_runtime.h>

// DissipativeRINN — fp32 baseline.
// B=2048 rows independent; 1 block (128 thr) per row.
// Thread j holds Dvw_T[:,j] in 128 VGPRs; w broadcast via LDS double buffer.

constexpr int B_TOT   = 2048;
constexpr int T_STEPS = 32;
constexpr int IN_D    = 16;
constexpr int ST_D    = 16;
constexpr int NL_D    = 128;
constexpr int OUT_D   = 8;
constexpr int H_D     = 64;
constexpr int OUT_C   = 17;   // 8 means + 8 log_std + 1 value
constexpr float DT_F  = 0.01f;

__device__ __forceinline__ float fast_tanh(float a) {
    // tanh(a) = 1 - 2/(exp(2a)+1); exp overflow/underflow saturates correctly.
    float e = __expf(2.0f * a);
    return 1.0f - 2.0f / (e + 1.0f);
}

__device__ __forceinline__ float bias_calc(const float* xv, float yD,
                                           const float* __restrict__ Cv_T, int j) {
    float b = yD;
#pragma unroll
    for (int k = 0; k < ST_D; ++k) b = fmaf(xv[k], Cv_T[k * NL_D + j], b);
    return b;
}

// w <- tanh(bias + w @ Dvw_T), niter times. w double-buffered in LDS.
__device__ __forceinline__ void fpi_iters(int niter, float bias,
                                          float (&wsh)[2][NL_D], int& cur,
                                          const float (&dcol)[NL_D], int j) {
#pragma unroll 1
    for (int it = 0; it < niter; ++it) {
        float acc = bias;
        const float4* w4 = reinterpret_cast<const float4*>(&wsh[cur][0]);
#pragma unroll
        for (int q = 0; q < NL_D / 4; ++q) {
            float4 wv = w4[q];                    // broadcast ds_read_b128
            acc = fmaf(wv.x, dcol[4 * q + 0], acc);
            acc = fmaf(wv.y, dcol[4 * q + 1], acc);
            acc = fmaf(wv.z, dcol[4 * q + 2], acc);
            acc = fmaf(wv.w, dcol[4 * q + 3], acc);
        }
        wsh[cur ^ 1][j] = fast_tanh(acc);
        cur ^= 1;
        __syncthreads();   // write of new buf visible; all reads of old buf done
    }
}

__device__ __forceinline__ float kcalc(const float* xv, float yBy,
                                       const float* __restrict__ A_T,
                                       const float* __restrict__ Bw_T,
                                       const float* w, int j) {
    float kv = yBy;
#pragma unroll
    for (int k = 0; k < ST_D; ++k) kv = fmaf(xv[k], A_T[k * ST_D + j], kv);
#pragma unroll
    for (int k = 0; k < NL_D; ++k) kv = fmaf(w[k], Bw_T[k * ST_D + j], kv);
    return kv;
}

__global__ void rinn_kernel(const float* __restrict__ obs,
                            const float* __restrict__ x0,
                            const float* __restrict__ A_T,
                            const float* __restrict__ Bw_T,
                            const float* __restrict__ By_T,
                            const float* __restrict__ Cv_T,
                            const float* __restrict__ Dvw_T,
                            const float* __restrict__ Dvy_T,
                            const float* __restrict__ Cu_T,
                            const float* __restrict__ Duw_T,
                            const float* __restrict__ Duy_T,
                            float* __restrict__ out) {
    const int b = blockIdx.x;
    const int j = threadIdx.x;   // 0..127

    __shared__ __align__(16) float wsh[2][NL_D];
    __shared__ float xsh[ST_D];
    __shared__ float xt[ST_D];
    __shared__ float ysh[IN_D];

    // Dvw column j -> registers (loaded once, reused 45*32 times)
    float dcol[NL_D];
#pragma unroll
    for (int k = 0; k < NL_D; ++k) dcol[k] = Dvw_T[k * NL_D + j];

    if (j < ST_D) xsh[j] = x0[b * ST_D + j];
    __syncthreads();

#pragma unroll 1
    for (int t = 0; t < T_STEPS; ++t) {
        if (j < IN_D) ysh[j] = obs[(b * T_STEPS + t) * IN_D + j];
        wsh[0][j] = 0.0f;        // w_init = zeros each step
        int cur = 0;
        __syncthreads();

        // y-derived terms (constant within the step)
        float yD = 0.0f;
#pragma unroll
        for (int k = 0; k < IN_D; ++k) yD = fmaf(ysh[k], Dvy_T[k * NL_D + j], yD);
        float yBy = 0.0f, yDuy = 0.0f;
        if (j < ST_D) {
#pragma unroll
            for (int k = 0; k < IN_D; ++k) yBy = fmaf(ysh[k], By_T[k * ST_D + j], yBy);
        }
        if (j < OUT_D) {
#pragma unroll
            for (int k = 0; k < IN_D; ++k) yDuy = fmaf(ysh[k], Duy_T[k * OUT_D + j], yDuy);
        }

        float k1 = 0.f, k2 = 0.f, k3 = 0.f, k4 = 0.f;

        // ---- xdot 1: x, 30 iters from w=0 ----
        float bias = bias_calc(xsh, yD, Cv_T, j);
        fpi_iters(30, bias, wsh, cur, dcol, j);
        {
            const float* w1 = &wsh[cur][0];
            if (j < OUT_D) {
                // u = x@Cu_T + w1@Duw_T + y@Duy_T  (controller output, current x)
                float u = yDuy;
#pragma unroll
                for (int k = 0; k < ST_D; ++k) u = fmaf(xsh[k], Cu_T[k * OUT_D + j], u);
#pragma unroll
                for (int k = 0; k < NL_D; ++k) u = fmaf(w1[k], Duw_T[k * OUT_D + j], u);
                out[(b * T_STEPS + t) * OUT_C + j] = u;
            }
            if (j < ST_D) {
                k1 = kcalc(xsh, yBy, A_T, Bw_T, w1, j);
                xt[j] = fmaf(0.5f * DT_F, k1, xsh[j]);
            }
        }
        __syncthreads();

        // ---- xdot 2: x + dt/2*k1, 5 iters (warm start w1) ----
        bias = bias_calc(xt, yD, Cv_T, j);
        fpi_iters(5, bias, wsh, cur, dcol, j);
        if (j < ST_D) k2 = kcalc(xt, yBy, A_T, Bw_T, &wsh[cur][0], j);
        __syncthreads();                       // all xt reads done before overwrite
        if (j < ST_D) xt[j] = fmaf(0.5f * DT_F, k2, xsh[j]);
        __syncthreads();

        // ---- xdot 3 ----
        bias = bias_calc(xt, yD, Cv_T, j);
        fpi_iters(5, bias, wsh, cur, dcol, j);
        if (j < ST_D) k3 = kcalc(xt, yBy, A_T, Bw_T, &wsh[cur][0], j);
        __syncthreads();
        if (j < ST_D) xt[j] = fmaf(DT_F, k3, xsh[j]);
        __syncthreads();

        // ---- xdot 4 ----
        bias = bias_calc(xt, yD, Cv_T, j);
        fpi_iters(5, bias, wsh, cur, dcol, j);
        if (j < ST_D) k4 = kcalc(xt, yBy, A_T, Bw_T, &wsh[cur][0], j);
        __syncthreads();

        if (j < ST_D)
            xsh[j] = fmaf(DT_F / 6.0f, k1 + 2.0f * k2 + 2.0f * k3 + k4, xsh[j]);
        __syncthreads();
    }
}

// value baseline MLP + log_std broadcast; one thread per (b,t)
__global__ __launch_bounds__(256) void mlp_kernel(
    const float* __restrict__ obs, const float* __restrict__ log_stds,
    const float* __restrict__ W1, const float* __restrict__ b1,
    const float* __restrict__ W2, const float* __restrict__ b2,
    const float* __restrict__ W3, const float* __restrict__ b3,
    float* __restrict__ out) {
    __shared__ float sW1[IN_D * H_D];
    __shared__ float sW2[H_D * H_D];
    __shared__ float sb1[H_D], sb2[H_D], sW3[H_D], sls[OUT_D];
    __shared__ float sb3;
    const int tid = threadIdx.x;
    for (int i = tid; i < IN_D * H_D; i += 256) sW1[i] = W1[i];
    for (int i = tid; i < H_D * H_D; i += 256) sW2[i] = W2[i];
    if (tid < H_D) { sb1[tid] = b1[tid]; sb2[tid] = b2[tid]; sW3[tid] = W3[tid]; }
    if (tid < OUT_D) sls[tid] = log_stds[tid];
    if (tid == 0) sb3 = b3[0];
    __syncthreads();

    const int bt = blockIdx.x * 256 + tid;
    if (bt >= B_TOT * T_STEPS) return;

    float o[IN_D];
#pragma unroll
    for (int i = 0; i < IN_D; ++i) o[i] = obs[bt * IN_D + i];

    float h1[H_D];
#pragma unroll
    for (int h = 0; h < H_D; ++h) {
        float a = sb1[h];
#pragma unroll
        for (int i = 0; i < IN_D; ++i) a = fmaf(o[i], sW1[i * H_D + h], a);
        h1[h] = fast_tanh(a);
    }
    float v = sb3;
#pragma unroll
    for (int h = 0; h < H_D; ++h) {
        float a = sb2[h];
#pragma unroll
        for (int i = 0; i < H_D; ++i) a = fmaf(h1[i], sW2[i * H_D + h], a);
        v = fmaf(fast_tanh(a), sW3[h], v);
    }

    float* o17 = out + bt * OUT_C;
#pragma unroll
    for (int q = 0; q < OUT_D; ++q) o17[OUT_D + q] = sls[q];
    o17[16] = v;
}

extern "C" void kernel_launch(void* const* d_in, const int* in_sizes, int n_in,
                              void* d_out, int out_size, void* d_ws, size_t ws_size,
                              hipStream_t stream) {
    const float* obs      = (const float*)d_in[0];
    const float* x0       = (const float*)d_in[1];
    const float* A_T      = (const float*)d_in[2];
    const float* Bw_T     = (const float*)d_in[3];
    const float* By_T     = (const float*)d_in[4];
    const float* Cv_T     = (const float*)d_in[5];
    const float* Dvw_T    = (const float*)d_in[6];
    const float* Dvy_T    = (const float*)d_in[7];
    const float* Cu_T     = (const float*)d_in[8];
    const float* Duw_T    = (const float*)d_in[9];
    const float* Duy_T    = (const float*)d_in[10];
    const float* log_stds = (const float*)d_in[11];
    const float* W1       = (const float*)d_in[12];
    const float* b1       = (const float*)d_in[13];
    const float* W2       = (const float*)d_in[14];
    const float* b2       = (const float*)d_in[15];
    const float* W3       = (const float*)d_in[16];
    const float* b3       = (const float*)d_in[17];
    float* out = (float*)d_out;

    rinn_kernel<<<dim3(B_TOT), dim3(NL_D), 0, stream>>>(
        obs, x0, A_T, Bw_T, By_T, Cv_T, Dvw_T, Dvy_T, Cu_T, Duw_T, Duy_T, out);
    mlp_kernel<<<dim3((B_TOT * T_STEPS + 255) / 256), dim3(256), 0, stream>>>(
        obs, log_stds, W1, b1, W2, b2, W3, b3, out);
}

// Round 2
// 9244.054 us; speedup vs baseline: 1.4237x; 1.4237x over previous
//
#include <hip/hip_runtime.h>

// DissipativeRINN — fp32, spill-free inner loop.
// B=2048 rows independent; 1 block (128 thr) per row.
// Thread j holds Dvw_T[:,j] in 32 float4 VGPR quads (forced via launch_bounds).
// w broadcast via LDS double buffer; one barrier per fixed-point iteration.

constexpr int B_TOT   = 2048;
constexpr int T_STEPS = 32;
constexpr int IN_D    = 16;
constexpr int ST_D    = 16;
constexpr int NL_D    = 128;
constexpr int OUT_D   = 8;
constexpr int H_D     = 64;
constexpr int OUT_C   = 17;   // 8 means + 8 log_std + 1 value
constexpr float DT_F  = 0.01f;

__device__ __forceinline__ float fast_tanh(float a) {
    // tanh(a) = 1 - 2/(exp(2a)+1); exp saturates correctly at +-inf.
    float e = __expf(2.0f * a);
    return 1.0f - 2.0f / (e + 1.0f);
}

__device__ __forceinline__ float bias_calc(const float* xv, float yD,
                                           const float* __restrict__ Cv_T, int j) {
    float b = yD;
#pragma unroll
    for (int k = 0; k < ST_D; ++k) b = fmaf(xv[k], Cv_T[k * NL_D + j], b);
    return b;
}

// w <- tanh(bias + w @ Dvw_T), niter times. w double-buffered in LDS.
// dcol4 MUST stay in VGPRs: all accesses are compile-time constant.
__device__ __forceinline__ void fpi_iters(int niter, float bias,
                                          float (&wsh)[2][NL_D], int& cur,
                                          const float4 (&dcol4)[NL_D / 4], int j) {
#pragma unroll 1
    for (int it = 0; it < niter; ++it) {
        // 4 independent accumulator chains (break fmaf dep latency)
        float a0 = bias, a1 = 0.0f, a2 = 0.0f, a3 = 0.0f;
        const float4* w4 = reinterpret_cast<const float4*>(&wsh[cur][0]);
#pragma unroll
        for (int q = 0; q < NL_D / 4; q += 4) {
            float4 w0 = w4[q + 0];
            float4 w1 = w4[q + 1];
            float4 w2 = w4[q + 2];
            float4 w3 = w4[q + 3];
            a0 = fmaf(w0.x, dcol4[q + 0].x, a0);
            a0 = fmaf(w0.y, dcol4[q + 0].y, a0);
            a0 = fmaf(w0.z, dcol4[q + 0].z, a0);
            a0 = fmaf(w0.w, dcol4[q + 0].w, a0);
            a1 = fmaf(w1.x, dcol4[q + 1].x, a1);
            a1 = fmaf(w1.y, dcol4[q + 1].y, a1);
            a1 = fmaf(w1.z, dcol4[q + 1].z, a1);
            a1 = fmaf(w1.w, dcol4[q + 1].w, a1);
            a2 = fmaf(w2.x, dcol4[q + 2].x, a2);
            a2 = fmaf(w2.y, dcol4[q + 2].y, a2);
            a2 = fmaf(w2.z, dcol4[q + 2].z, a2);
            a2 = fmaf(w2.w, dcol4[q + 2].w, a2);
            a3 = fmaf(w3.x, dcol4[q + 3].x, a3);
            a3 = fmaf(w3.y, dcol4[q + 3].y, a3);
            a3 = fmaf(w3.z, dcol4[q + 3].z, a3);
            a3 = fmaf(w3.w, dcol4[q + 3].w, a3);
        }
        float acc = (a0 + a1) + (a2 + a3);
        wsh[cur ^ 1][j] = fast_tanh(acc);
        cur ^= 1;
        __syncthreads();   // new buf visible; all reads of old buf done
    }
}

__device__ __forceinline__ float kcalc(const float* xv, float yBy,
                                       const float* __restrict__ A_T,
                                       const float* __restrict__ Bw_T,
                                       const float* w, int j) {
    float kv = yBy;
#pragma unroll
    for (int k = 0; k < ST_D; ++k) kv = fmaf(xv[k], A_T[k * ST_D + j], kv);
#pragma unroll
    for (int k = 0; k < NL_D; ++k) kv = fmaf(w[k], Bw_T[k * ST_D + j], kv);
    return kv;
}

__global__ __launch_bounds__(128, 1) void rinn_kernel(
                            const float* __restrict__ obs,
                            const float* __restrict__ x0,
                            const float* __restrict__ A_T,
                            const float* __restrict__ Bw_T,
                            const float* __restrict__ By_T,
                            const float* __restrict__ Cv_T,
                            const float* __restrict__ Dvw_T,
                            const float* __restrict__ Dvy_T,
                            const float* __restrict__ Cu_T,
                            const float* __restrict__ Duw_T,
                            const float* __restrict__ Duy_T,
                            float* __restrict__ out) {
    const int b = blockIdx.x;
    const int j = threadIdx.x;   // 0..127

    __shared__ __align__(16) float wsh[2][NL_D];
    __shared__ float xsh[ST_D];
    __shared__ float xt[ST_D];
    __shared__ float ysh[IN_D];

    // Dvw column j -> 32 float4 register quads (loaded once, reused 45*32x)
    float4 dcol4[NL_D / 4];
#pragma unroll
    for (int q = 0; q < NL_D / 4; ++q) {
        dcol4[q].x = Dvw_T[(4 * q + 0) * NL_D + j];
        dcol4[q].y = Dvw_T[(4 * q + 1) * NL_D + j];
        dcol4[q].z = Dvw_T[(4 * q + 2) * NL_D + j];
        dcol4[q].w = Dvw_T[(4 * q + 3) * NL_D + j];
    }

    if (j < ST_D) xsh[j] = x0[b * ST_D + j];
    __syncthreads();

#pragma unroll 1
    for (int t = 0; t < T_STEPS; ++t) {
        if (j < IN_D) ysh[j] = obs[(b * T_STEPS + t) * IN_D + j];
        wsh[0][j] = 0.0f;        // w_init = zeros each step
        int cur = 0;
        __syncthreads();

        // y-derived terms (constant within the step)
        float yD = 0.0f;
#pragma unroll
        for (int k = 0; k < IN_D; ++k) yD = fmaf(ysh[k], Dvy_T[k * NL_D + j], yD);
        float yBy = 0.0f, yDuy = 0.0f;
        if (j < ST_D) {
#pragma unroll
            for (int k = 0; k < IN_D; ++k) yBy = fmaf(ysh[k], By_T[k * ST_D + j], yBy);
        }
        if (j < OUT_D) {
#pragma unroll
            for (int k = 0; k < IN_D; ++k) yDuy = fmaf(ysh[k], Duy_T[k * OUT_D + j], yDuy);
        }

        float k1 = 0.f, k2 = 0.f, k3 = 0.f, k4 = 0.f;

        // ---- xdot 1: x, 30 iters from w=0 ----
        float bias = bias_calc(xsh, yD, Cv_T, j);
        fpi_iters(30, bias, wsh, cur, dcol4, j);
        {
            const float* w1 = &wsh[cur][0];
            if (j < OUT_D) {
                // u = x@Cu_T + w1@Duw_T + y@Duy_T (controller output, current x)
                float u = yDuy;
#pragma unroll
                for (int k = 0; k < ST_D; ++k) u = fmaf(xsh[k], Cu_T[k * OUT_D + j], u);
#pragma unroll
                for (int k = 0; k < NL_D; ++k) u = fmaf(w1[k], Duw_T[k * OUT_D + j], u);
                out[(b * T_STEPS + t) * OUT_C + j] = u;
            }
            if (j < ST_D) {
                k1 = kcalc(xsh, yBy, A_T, Bw_T, w1, j);
                xt[j] = fmaf(0.5f * DT_F, k1, xsh[j]);
            }
        }
        __syncthreads();

        // ---- xdot 2: x + dt/2*k1, 5 iters (warm start) ----
        bias = bias_calc(xt, yD, Cv_T, j);
        fpi_iters(5, bias, wsh, cur, dcol4, j);
        if (j < ST_D) k2 = kcalc(xt, yBy, A_T, Bw_T, &wsh[cur][0], j);
        __syncthreads();                       // xt reads done before overwrite
        if (j < ST_D) xt[j] = fmaf(0.5f * DT_F, k2, xsh[j]);
        __syncthreads();

        // ---- xdot 3 ----
        bias = bias_calc(xt, yD, Cv_T, j);
        fpi_iters(5, bias, wsh, cur, dcol4, j);
        if (j < ST_D) k3 = kcalc(xt, yBy, A_T, Bw_T, &wsh[cur][0], j);
        __syncthreads();
        if (j < ST_D) xt[j] = fmaf(DT_F, k3, xsh[j]);
        __syncthreads();

        // ---- xdot 4 ----
        bias = bias_calc(xt, yD, Cv_T, j);
        fpi_iters(5, bias, wsh, cur, dcol4, j);
        if (j < ST_D) k4 = kcalc(xt, yBy, A_T, Bw_T, &wsh[cur][0], j);
        __syncthreads();

        if (j < ST_D)
            xsh[j] = fmaf(DT_F / 6.0f, k1 + 2.0f * k2 + 2.0f * k3 + k4, xsh[j]);
        __syncthreads();
    }
}

// value baseline MLP + log_std broadcast; one thread per (b,t)
__global__ __launch_bounds__(256) void mlp_kernel(
    const float* __restrict__ obs, const float* __restrict__ log_stds,
    const float* __restrict__ W1, const float* __restrict__ b1,
    const float* __restrict__ W2, const float* __restrict__ b2,
    const float* __restrict__ W3, const float* __restrict__ b3,
    float* __restrict__ out) {
    __shared__ float sW1[IN_D * H_D];
    __shared__ float sW2[H_D * H_D];
    __shared__ float sb1[H_D], sb2[H_D], sW3[H_D], sls[OUT_D];
    __shared__ float sb3;
    const int tid = threadIdx.x;
    for (int i = tid; i < IN_D * H_D; i += 256) sW1[i] = W1[i];
    for (int i = tid; i < H_D * H_D; i += 256) sW2[i] = W2[i];
    if (tid < H_D) { sb1[tid] = b1[tid]; sb2[tid] = b2[tid]; sW3[tid] = W3[tid]; }
    if (tid < OUT_D) sls[tid] = log_stds[tid];
    if (tid == 0) sb3 = b3[0];
    __syncthreads();

    const int bt = blockIdx.x * 256 + tid;
    if (bt >= B_TOT * T_STEPS) return;

    float o[IN_D];
#pragma unroll
    for (int i = 0; i < IN_D; ++i) o[i] = obs[bt * IN_D + i];

    float h1[H_D];
#pragma unroll
    for (int h = 0; h < H_D; ++h) {
        float a = sb1[h];
#pragma unroll
        for (int i = 0; i < IN_D; ++i) a = fmaf(o[i], sW1[i * H_D + h], a);
        h1[h] = fast_tanh(a);
    }
    float v = sb3;
#pragma unroll
    for (int h = 0; h < H_D; ++h) {
        float a = sb2[h];
#pragma unroll
        for (int i = 0; i < H_D; ++i) a = fmaf(h1[i], sW2[i * H_D + h], a);
        v = fmaf(fast_tanh(a), sW3[h], v);
    }

    float* o17 = out + bt * OUT_C;
#pragma unroll
    for (int q = 0; q < OUT_D; ++q) o17[OUT_D + q] = sls[q];
    o17[16] = v;
}

extern "C" void kernel_launch(void* const* d_in, const int* in_sizes, int n_in,
                              void* d_out, int out_size, void* d_ws, size_t ws_size,
                              hipStream_t stream) {
    const float* obs      = (const float*)d_in[0];
    const float* x0       = (const float*)d_in[1];
    const float* A_T      = (const float*)d_in[2];
    const float* Bw_T     = (const float*)d_in[3];
    const float* By_T     = (const float*)d_in[4];
    const float* Cv_T     = (const float*)d_in[5];
    const float* Dvw_T    = (const float*)d_in[6];
    const float* Dvy_T    = (const float*)d_in[7];
    const float* Cu_T     = (const float*)d_in[8];
    const float* Duw_T    = (const float*)d_in[9];
    const float* Duy_T    = (const float*)d_in[10];
    const float* log_stds = (const float*)d_in[11];
    const float* W1       = (const float*)d_in[12];
    const float* b1       = (const float*)d_in[13];
    const float* W2       = (const float*)d_in[14];
    const float* b2       = (const float*)d_in[15];
    const float* W3       = (const float*)d_in[16];
    const float* b3       = (const float*)d_in[17];
    float* out = (float*)d_out;

    rinn_kernel<<<dim3(B_TOT), dim3(NL_D), 0, stream>>>(
        obs, x0, A_T, Bw_T, By_T, Cv_T, Dvw_T, Dvy_T, Cu_T, Duw_T, Duy_T, out);
    mlp_kernel<<<dim3((B_TOT * T_STEPS + 255) / 256), dim3(256), 0, stream>>>(
        obs, log_stds, W1, b1, W2, b2, W3, b3, out);
}

// Round 3
// 3357.759 us; speedup vs baseline: 3.9194x; 2.7530x over previous
//
#include <hip/hip_runtime.h>

// DissipativeRINN — fp32, R=2 rows per block.
// 1024 blocks x 128 threads; thread j holds Dvw_T[:,j] in 32 float4 VGPRs,
// serves 2 batch rows per iteration (2x issue density per barrier).
// w double-buffered in LDS, broadcast ds_read_b128.

constexpr int B_TOT   = 2048;
constexpr int T_STEPS = 32;
constexpr int IN_D    = 16;
constexpr int ST_D    = 16;
constexpr int NL_D    = 128;
constexpr int OUT_D   = 8;
constexpr int H_D     = 64;
constexpr int OUT_C   = 17;   // 8 means + 8 log_std + 1 value
constexpr float DT_F  = 0.01f;
constexpr int R       = 2;    // rows per block

__device__ __forceinline__ float fast_tanh(float a) {
    float e = __expf(2.0f * a);
    return 1.0f - 2.0f / (e + 1.0f);
}

// w[r] <- tanh(bias[r] + w[r] @ Dvw_T), niter times, both rows per barrier.
__device__ __forceinline__ void fpi_iters(int niter, const float (&bias)[R],
                                          float (&wsh)[2][R][NL_D], int& cur,
                                          const float4 (&dcol4)[NL_D / 4], int j) {
#pragma unroll 1
    for (int it = 0; it < niter; ++it) {
        // 2 chains per row -> 4 independent accumulators
        float a0_0 = bias[0], a1_0 = 0.0f;
        float a0_1 = bias[1], a1_1 = 0.0f;
        const float4* wa = reinterpret_cast<const float4*>(&wsh[cur][0][0]);
        const float4* wb = reinterpret_cast<const float4*>(&wsh[cur][1][0]);
#pragma unroll
        for (int q = 0; q < NL_D / 4; q += 2) {
            float4 u0 = wa[q],     v0 = wb[q];
            float4 u1 = wa[q + 1], v1 = wb[q + 1];
            float4 d0 = dcol4[q], d1 = dcol4[q + 1];
            a0_0 = fmaf(u0.x, d0.x, a0_0);
            a0_0 = fmaf(u0.y, d0.y, a0_0);
            a0_0 = fmaf(u0.z, d0.z, a0_0);
            a0_0 = fmaf(u0.w, d0.w, a0_0);
            a0_1 = fmaf(v0.x, d0.x, a0_1);
            a0_1 = fmaf(v0.y, d0.y, a0_1);
            a0_1 = fmaf(v0.z, d0.z, a0_1);
            a0_1 = fmaf(v0.w, d0.w, a0_1);
            a1_0 = fmaf(u1.x, d1.x, a1_0);
            a1_0 = fmaf(u1.y, d1.y, a1_0);
            a1_0 = fmaf(u1.z, d1.z, a1_0);
            a1_0 = fmaf(u1.w, d1.w, a1_0);
            a1_1 = fmaf(v1.x, d1.x, a1_1);
            a1_1 = fmaf(v1.y, d1.y, a1_1);
            a1_1 = fmaf(v1.z, d1.z, a1_1);
            a1_1 = fmaf(v1.w, d1.w, a1_1);
        }
        int nxt = cur ^ 1;
        wsh[nxt][0][j] = fast_tanh(a0_0 + a1_0);
        wsh[nxt][1][j] = fast_tanh(a0_1 + a1_1);
        cur = nxt;
        __syncthreads();
    }
}

__device__ __forceinline__ float kcalc(const float* xv, float yBy,
                                       const float* __restrict__ A_T,
                                       const float* __restrict__ Bw_T,
                                       const float* w, int j) {
    float kv = yBy;
#pragma unroll
    for (int k = 0; k < ST_D; ++k) kv = fmaf(xv[k], A_T[k * ST_D + j], kv);
#pragma unroll
    for (int k = 0; k < NL_D; ++k) kv = fmaf(w[k], Bw_T[k * ST_D + j], kv);
    return kv;
}

__global__ __launch_bounds__(128, 2) void rinn_kernel(
                            const float* __restrict__ obs,
                            const float* __restrict__ x0,
                            const float* __restrict__ A_T,
                            const float* __restrict__ Bw_T,
                            const float* __restrict__ By_T,
                            const float* __restrict__ Cv_T,
                            const float* __restrict__ Dvw_T,
                            const float* __restrict__ Dvy_T,
                            const float* __restrict__ Cu_T,
                            const float* __restrict__ Duw_T,
                            const float* __restrict__ Duy_T,
                            float* __restrict__ out) {
    const int b0 = blockIdx.x * R;   // first batch row of this block
    const int j  = threadIdx.x;      // 0..127

    __shared__ __align__(16) float wsh[2][R][NL_D];
    __shared__ float xsh[R][ST_D];
    __shared__ float xt[R][ST_D];
    __shared__ float ysh[R][IN_D];

    // Dvw column j -> 32 float4 register quads (reused 45*32*R times)
    float4 dcol4[NL_D / 4];
#pragma unroll
    for (int q = 0; q < NL_D / 4; ++q) {
        dcol4[q].x = Dvw_T[(4 * q + 0) * NL_D + j];
        dcol4[q].y = Dvw_T[(4 * q + 1) * NL_D + j];
        dcol4[q].z = Dvw_T[(4 * q + 2) * NL_D + j];
        dcol4[q].w = Dvw_T[(4 * q + 3) * NL_D + j];
    }

    if (j < ST_D) {
#pragma unroll
        for (int r = 0; r < R; ++r) xsh[r][j] = x0[(b0 + r) * ST_D + j];
    }
    __syncthreads();

#pragma unroll 1
    for (int t = 0; t < T_STEPS; ++t) {
        if (j < IN_D) {
#pragma unroll
            for (int r = 0; r < R; ++r)
                ysh[r][j] = obs[((b0 + r) * T_STEPS + t) * IN_D + j];
        }
#pragma unroll
        for (int r = 0; r < R; ++r) wsh[0][r][j] = 0.0f;
        int cur = 0;
        __syncthreads();

        // y-derived terms (constant within the step)
        float yD[R], yBy[R], yDuy[R];
#pragma unroll
        for (int r = 0; r < R; ++r) {
            float s = 0.0f;
#pragma unroll
            for (int k = 0; k < IN_D; ++k) s = fmaf(ysh[r][k], Dvy_T[k * NL_D + j], s);
            yD[r] = s;
            yBy[r] = 0.0f;
            yDuy[r] = 0.0f;
        }
        if (j < ST_D) {
#pragma unroll
            for (int r = 0; r < R; ++r) {
                float s = 0.0f;
#pragma unroll
                for (int k = 0; k < IN_D; ++k) s = fmaf(ysh[r][k], By_T[k * ST_D + j], s);
                yBy[r] = s;
            }
        }
        if (j < OUT_D) {
#pragma unroll
            for (int r = 0; r < R; ++r) {
                float s = 0.0f;
#pragma unroll
                for (int k = 0; k < IN_D; ++k) s = fmaf(ysh[r][k], Duy_T[k * OUT_D + j], s);
                yDuy[r] = s;
            }
        }

        float k1[R], k2[R], k3[R], k4[R];
        float bias[R];

        // ---- stage 1: x, 30 iters from w=0 ----
#pragma unroll
        for (int r = 0; r < R; ++r) {
            float bsum = yD[r];
#pragma unroll
            for (int k = 0; k < ST_D; ++k) bsum = fmaf(xsh[r][k], Cv_T[k * NL_D + j], bsum);
            bias[r] = bsum;
        }
        fpi_iters(30, bias, wsh, cur, dcol4, j);
        if (j < OUT_D) {
#pragma unroll
            for (int r = 0; r < R; ++r) {
                const float* w1 = &wsh[cur][r][0];
                float u = yDuy[r];
#pragma unroll
                for (int k = 0; k < ST_D; ++k) u = fmaf(xsh[r][k], Cu_T[k * OUT_D + j], u);
#pragma unroll
                for (int k = 0; k < NL_D; ++k) u = fmaf(w1[k], Duw_T[k * OUT_D + j], u);
                out[((b0 + r) * T_STEPS + t) * OUT_C + j] = u;
            }
        }
        if (j < ST_D) {
#pragma unroll
            for (int r = 0; r < R; ++r) {
                k1[r] = kcalc(&xsh[r][0], yBy[r], A_T, Bw_T, &wsh[cur][r][0], j);
                xt[r][j] = fmaf(0.5f * DT_F, k1[r], xsh[r][j]);
            }
        }
        __syncthreads();

        // ---- stage 2: x + dt/2*k1, 5 iters (warm start) ----
#pragma unroll
        for (int r = 0; r < R; ++r) {
            float bsum = yD[r];
#pragma unroll
            for (int k = 0; k < ST_D; ++k) bsum = fmaf(xt[r][k], Cv_T[k * NL_D + j], bsum);
            bias[r] = bsum;
        }
        fpi_iters(5, bias, wsh, cur, dcol4, j);
        if (j < ST_D) {
#pragma unroll
            for (int r = 0; r < R; ++r)
                k2[r] = kcalc(&xt[r][0], yBy[r], A_T, Bw_T, &wsh[cur][r][0], j);
        }
        __syncthreads();          // xt reads done before overwrite
        if (j < ST_D) {
#pragma unroll
            for (int r = 0; r < R; ++r) xt[r][j] = fmaf(0.5f * DT_F, k2[r], xsh[r][j]);
        }
        __syncthreads();

        // ---- stage 3 ----
#pragma unroll
        for (int r = 0; r < R; ++r) {
            float bsum = yD[r];
#pragma unroll
            for (int k = 0; k < ST_D; ++k) bsum = fmaf(xt[r][k], Cv_T[k * NL_D + j], bsum);
            bias[r] = bsum;
        }
        fpi_iters(5, bias, wsh, cur, dcol4, j);
        if (j < ST_D) {
#pragma unroll
            for (int r = 0; r < R; ++r)
                k3[r] = kcalc(&xt[r][0], yBy[r], A_T, Bw_T, &wsh[cur][r][0], j);
        }
        __syncthreads();
        if (j < ST_D) {
#pragma unroll
            for (int r = 0; r < R; ++r) xt[r][j] = fmaf(DT_F, k3[r], xsh[r][j]);
        }
        __syncthreads();

        // ---- stage 4 ----
#pragma unroll
        for (int r = 0; r < R; ++r) {
            float bsum = yD[r];
#pragma unroll
            for (int k = 0; k < ST_D; ++k) bsum = fmaf(xt[r][k], Cv_T[k * NL_D + j], bsum);
            bias[r] = bsum;
        }
        fpi_iters(5, bias, wsh, cur, dcol4, j);
        if (j < ST_D) {
#pragma unroll
            for (int r = 0; r < R; ++r)
                k4[r] = kcalc(&xt[r][0], yBy[r], A_T, Bw_T, &wsh[cur][r][0], j);
        }
        __syncthreads();

        if (j < ST_D) {
#pragma unroll
            for (int r = 0; r < R; ++r)
                xsh[r][j] = fmaf(DT_F / 6.0f,
                                 k1[r] + 2.0f * k2[r] + 2.0f * k3[r] + k4[r],
                                 xsh[r][j]);
        }
        __syncthreads();
    }
}

// value baseline MLP + log_std broadcast; one thread per (b,t)
__global__ __launch_bounds__(256) void mlp_kernel(
    const float* __restrict__ obs, const float* __restrict__ log_stds,
    const float* __restrict__ W1, const float* __restrict__ b1,
    const float* __restrict__ W2, const float* __restrict__ b2,
    const float* __restrict__ W3, const float* __restrict__ b3,
    float* __restrict__ out) {
    __shared__ float sW1[IN_D * H_D];
    __shared__ float sW2[H_D * H_D];
    __shared__ float sb1[H_D], sb2[H_D], sW3[H_D], sls[OUT_D];
    __shared__ float sb3;
    const int tid = threadIdx.x;
    for (int i = tid; i < IN_D * H_D; i += 256) sW1[i] = W1[i];
    for (int i = tid; i < H_D * H_D; i += 256) sW2[i] = W2[i];
    if (tid < H_D) { sb1[tid] = b1[tid]; sb2[tid] = b2[tid]; sW3[tid] = W3[tid]; }
    if (tid < OUT_D) sls[tid] = log_stds[tid];
    if (tid == 0) sb3 = b3[0];
    __syncthreads();

    const int bt = blockIdx.x * 256 + tid;
    if (bt >= B_TOT * T_STEPS) return;

    float o[IN_D];
#pragma unroll
    for (int i = 0; i < IN_D; ++i) o[i] = obs[bt * IN_D + i];

    float h1[H_D];
#pragma unroll
    for (int h = 0; h < H_D; ++h) {
        float a = sb1[h];
#pragma unroll
        for (int i = 0; i < IN_D; ++i) a = fmaf(o[i], sW1[i * H_D + h], a);
        h1[h] = fast_tanh(a);
    }
    float v = sb3;
#pragma unroll
    for (int h = 0; h < H_D; ++h) {
        float a = sb2[h];
#pragma unroll
        for (int i = 0; i < H_D; ++i) a = fmaf(h1[i], sW2[i * H_D + h], a);
        v = fmaf(fast_tanh(a), sW3[h], v);
    }

    float* o17 = out + bt * OUT_C;
#pragma unroll
    for (int q = 0; q < OUT_D; ++q) o17[OUT_D + q] = sls[q];
    o17[16] = v;
}

extern "C" void kernel_launch(void* const* d_in, const int* in_sizes, int n_in,
                              void* d_out, int out_size, void* d_ws, size_t ws_size,
                              hipStream_t stream) {
    const float* obs      = (const float*)d_in[0];
    const float* x0       = (const float*)d_in[1];
    const float* A_T      = (const float*)d_in[2];
    const float* Bw_T     = (const float*)d_in[3];
    const float* By_T     = (const float*)d_in[4];
    const float* Cv_T     = (const float*)d_in[5];
    const float* Dvw_T    = (const float*)d_in[6];
    const float* Dvy_T    = (const float*)d_in[7];
    const float* Cu_T     = (const float*)d_in[8];
    const float* Duw_T    = (const float*)d_in[9];
    const float* Duy_T    = (const float*)d_in[10];
    const float* log_stds = (const float*)d_in[11];
    const float* W1       = (const float*)d_in[12];
    const float* b1       = (const float*)d_in[13];
    const float* W2       = (const float*)d_in[14];
    const float* b2       = (const float*)d_in[15];
    const float* W3       = (const float*)d_in[16];
    const float* b3       = (const float*)d_in[17];
    float* out = (float*)d_out;

    rinn_kernel<<<dim3(B_TOT / R), dim3(NL_D), 0, stream>>>(
        obs, x0, A_T, Bw_T, By_T, Cv_T, Dvw_T, Dvy_T, Cu_T, Duw_T, Duy_T, out);
    mlp_kernel<<<dim3((B_TOT * T_STEPS + 255) / 256), dim3(256), 0, stream>>>(
        obs, log_stds, W1, b1, W2, b2, W3, b3, out);
}

// Round 4
// 1521.414 us; speedup vs baseline: 8.6501x; 2.2070x over previous
//
#include <hip/hip_runtime.h>

// DissipativeRINN — fp16 MFMA fixed-point iteration.
// 256 blocks x 4 independent waves; each wave = 2 batch rows padded to M=16.
// Dvw (and bias matrices) live in VGPR B-fragments; w round-trips through a
// per-wave swizzled LDS tile (no barriers: single-wave in-order DS).

typedef _Float16 f16x8 __attribute__((ext_vector_type(8)));
typedef float f32x4 __attribute__((ext_vector_type(4)));

constexpr int B_TOT   = 2048;
constexpr int T_STEPS = 32;
constexpr int IN_D    = 16;
constexpr int ST_D    = 16;
constexpr int NL_D    = 128;
constexpr int OUT_D   = 8;
constexpr int H_D     = 64;
constexpr int OUT_C   = 17;   // 8 means + 8 log_std + 1 value
constexpr float DT_F  = 0.01f;

constexpr int LDS_PER_WAVE = 5120;   // w[16][128] f16 (4096B) + xy[16][32] f16 (1024B)
constexpr int XY_OFF = 4096;

__device__ __forceinline__ f16x8 ld_h8(const char* p) {
    return __builtin_bit_cast(f16x8, *(const f32x4*)p);   // ds_read_b128
}

__global__ __launch_bounds__(256, 1) void rinn_mfma(
    const float* __restrict__ obs, const float* __restrict__ x0,
    const float* __restrict__ A_T, const float* __restrict__ Bw_T,
    const float* __restrict__ By_T, const float* __restrict__ Cv_T,
    const float* __restrict__ Dvw_T, const float* __restrict__ Dvy_T,
    const float* __restrict__ Cu_T, const float* __restrict__ Duw_T,
    const float* __restrict__ Duy_T, float* __restrict__ out)
{
    __shared__ __align__(16) char lds_all[4][LDS_PER_WAVE];
    const int wid  = threadIdx.x >> 6;
    const int lane = threadIdx.x & 63;
    const int g    = lane >> 4;     // k-group 0..3
    const int c16  = lane & 15;     // tile col (B/C) or A row
    const int b0   = blockIdx.x * 8 + wid * 2;
    char* W = lds_all[wid];

    const f32x4 z4 = {0.f, 0.f, 0.f, 0.f};

    // ---- B fragments (resident in VGPRs for the whole kernel) ----
    // B layout for 16x16x32: lane l holds B[kstep*32 + (l>>4)*8 + j][ntile*16 + (l&15)]
    f16x8 bD[4][8];   // Dvw, scaled by 2 (tanh exp trick)
    f16x8 bBias[8];   // [Cv;Dvy] K=32, scaled by 2
    f16x8 bK[5];      // [A_T;By_T;Bw_T] K=160 -> k (16 cols)
    f16x8 bU[5];      // [Cu_T;Duy_T;Duw_T] K=160 -> u (8 valid cols)
#pragma unroll
    for (int s = 0; s < 4; ++s)
#pragma unroll
        for (int n = 0; n < 8; ++n) {
            f16x8 h;
#pragma unroll
            for (int j = 0; j < 8; ++j)
                h[j] = (_Float16)(2.0f * Dvw_T[(s*32 + g*8 + j)*NL_D + n*16 + c16]);
            bD[s][n] = h;
        }
#pragma unroll
    for (int n = 0; n < 8; ++n) {
        f16x8 h;
#pragma unroll
        for (int j = 0; j < 8; ++j) {
            int k = g*8 + j;
            float v = (k < 16) ? Cv_T[k*NL_D + n*16 + c16]
                               : Dvy_T[(k-16)*NL_D + n*16 + c16];
            h[j] = (_Float16)(2.0f * v);
        }
        bBias[n] = h;
    }
#pragma unroll
    for (int s = 0; s < 5; ++s) {
        f16x8 hk, hu;
#pragma unroll
        for (int j = 0; j < 8; ++j) {
            int k = s*32 + g*8 + j;
            float vk, vu;
            if (k < 16)      { vk = A_T[k*ST_D + c16];       vu = (c16 < OUT_D) ? Cu_T[k*OUT_D + c16] : 0.f; }
            else if (k < 32) { vk = By_T[(k-16)*ST_D + c16]; vu = (c16 < OUT_D) ? Duy_T[(k-16)*OUT_D + c16] : 0.f; }
            else             { vk = Bw_T[(k-32)*ST_D + c16]; vu = (c16 < OUT_D) ? Duw_T[(k-32)*OUT_D + c16] : 0.f; }
            hk[j] = (_Float16)vk; hu[j] = (_Float16)vu;
        }
        bK[s] = hk; bU[s] = hu;
    }

    // ---- LDS offsets (XOR swizzle vs 16-way row-stride conflicts) ----
    // w tile: [16 rows][128 k] f16, 256 B/row; slot = 16B; slot ^= row&7
    auto w_rd_off = [&](int s) -> int {
        int row = c16;
        return row*256 + ((s*64 + g*16) ^ ((row & 7) << 4));
    };
    auto w_wr_off = [&](int rr, int col) -> int {
        return rr*256 + ((col*2) ^ ((rr & 7) << 4));
    };
    // xy tile: [16 rows][32 cols] f16 (x:0-15, y:16-31), 64 B/row; slot ^= row&3
    auto xy_rd_off = [&]() -> int {
        int row = c16;
        return XY_OFF + row*64 + ((g*16) ^ ((row & 3) << 4));
    };
    auto xy_wr_off = [&](int rr, int col) -> int {
        return XY_OFF + rr*64 + ((col*2) ^ ((rr & 3) << 4));
    };

    // ---- zero-init per-wave LDS (pad rows 2-15 must read as 0 forever) ----
#pragma unroll
    for (int q = 0; q < 4; ++q) *(f32x4*)(W + lane*64 + q*16) = z4;  // 4 KB w
    *(f32x4*)(W + XY_OFF + lane*16) = z4;                            // 1 KB xy

    // ---- x state (f32 regs, lanes 0-15 hold col=lane for rows 0,1) ----
    float xb[2] = {0.f, 0.f};
    if (lane < 16) {
#pragma unroll
        for (int rr = 0; rr < 2; ++rr) {
            xb[rr] = x0[(b0+rr)*ST_D + lane];
            *(_Float16*)(W + xy_wr_off(rr, lane)) = (_Float16)xb[rr];
        }
    }

    f32x4 biasAcc[8];
    auto calc_bias = [&]() {
        f16x8 aXY = ld_h8(W + xy_rd_off());
#pragma unroll
        for (int n = 0; n < 8; ++n)
            biasAcc[n] = __builtin_amdgcn_mfma_f32_16x16x32_f16(aXY, bBias[n], z4, 0, 0, 0);
    };

    auto fpi = [&](int niter) {
#pragma unroll 1
        for (int it = 0; it < niter; ++it) {
            f16x8 a0 = ld_h8(W + w_rd_off(0));
            f16x8 a1 = ld_h8(W + w_rd_off(1));
            f16x8 a2 = ld_h8(W + w_rd_off(2));
            f16x8 a3 = ld_h8(W + w_rd_off(3));
#pragma unroll
            for (int n = 0; n < 8; ++n) {
                f32x4 t = __builtin_amdgcn_mfma_f32_16x16x32_f16(a0, bD[0][n], biasAcc[n], 0,0,0);
                t = __builtin_amdgcn_mfma_f32_16x16x32_f16(a1, bD[1][n], t, 0,0,0);
                t = __builtin_amdgcn_mfma_f32_16x16x32_f16(a2, bD[2][n], t, 0,0,0);
                t = __builtin_amdgcn_mfma_f32_16x16x32_f16(a3, bD[3][n], t, 0,0,0);
                // acc = 2*(bias + w@D); tanh(a) = 1 - 2/(1+e^{2a})
                if (lane < 16) {
#pragma unroll
                    for (int rr = 0; rr < 2; ++rr) {
                        float e  = __expf(t[rr]);
                        float wv = 1.0f - __fdividef(2.0f, 1.0f + e);
                        *(_Float16*)(W + w_wr_off(rr, n*16 + c16)) = (_Float16)wv;
                    }
                }
            }
        }
    };

    f32x4 accK, accU;
    auto epilogue = [&]() {
        f16x8 aXY = ld_h8(W + xy_rd_off());
        f16x8 a0 = ld_h8(W + w_rd_off(0));
        f16x8 a1 = ld_h8(W + w_rd_off(1));
        f16x8 a2 = ld_h8(W + w_rd_off(2));
        f16x8 a3 = ld_h8(W + w_rd_off(3));
        accK = __builtin_amdgcn_mfma_f32_16x16x32_f16(aXY, bK[0], z4, 0,0,0);
        accK = __builtin_amdgcn_mfma_f32_16x16x32_f16(a0, bK[1], accK, 0,0,0);
        accK = __builtin_amdgcn_mfma_f32_16x16x32_f16(a1, bK[2], accK, 0,0,0);
        accK = __builtin_amdgcn_mfma_f32_16x16x32_f16(a2, bK[3], accK, 0,0,0);
        accK = __builtin_amdgcn_mfma_f32_16x16x32_f16(a3, bK[4], accK, 0,0,0);
        accU = __builtin_amdgcn_mfma_f32_16x16x32_f16(aXY, bU[0], z4, 0,0,0);
        accU = __builtin_amdgcn_mfma_f32_16x16x32_f16(a0, bU[1], accU, 0,0,0);
        accU = __builtin_amdgcn_mfma_f32_16x16x32_f16(a1, bU[2], accU, 0,0,0);
        accU = __builtin_amdgcn_mfma_f32_16x16x32_f16(a2, bU[3], accU, 0,0,0);
        accU = __builtin_amdgcn_mfma_f32_16x16x32_f16(a3, bU[4], accU, 0,0,0);
    };

    float k1[2], k2[2], k3[2], k4[2];

#pragma unroll 1
    for (int t = 0; t < T_STEPS; ++t) {
        // w_init = zeros (rows 0,1 = bytes 0..511)
        if (lane < 32) *(f32x4*)(W + lane*16) = z4;
        // y rows 0,1 for this step
        if (lane < 16) {
#pragma unroll
            for (int rr = 0; rr < 2; ++rr) {
                float yv = obs[((b0+rr)*T_STEPS + t)*IN_D + lane];
                *(_Float16*)(W + xy_wr_off(rr, 16 + lane)) = (_Float16)yv;
            }
        }

        // ---- stage 1: x = xb, 30 iters from w=0; emit u and k1 ----
        calc_bias(); fpi(30); epilogue();
        if (lane < OUT_D) {
#pragma unroll
            for (int rr = 0; rr < 2; ++rr)
                out[((b0+rr)*T_STEPS + t)*OUT_C + lane] = accU[rr];
        }
        if (lane < 16) {
#pragma unroll
            for (int rr = 0; rr < 2; ++rr) {
                k1[rr] = accK[rr];
                float xc = fmaf(0.5f*DT_F, k1[rr], xb[rr]);
                *(_Float16*)(W + xy_wr_off(rr, lane)) = (_Float16)xc;
            }
        }
        // ---- stage 2 ----
        calc_bias(); fpi(5); epilogue();
        if (lane < 16) {
#pragma unroll
            for (int rr = 0; rr < 2; ++rr) {
                k2[rr] = accK[rr];
                float xc = fmaf(0.5f*DT_F, k2[rr], xb[rr]);
                *(_Float16*)(W + xy_wr_off(rr, lane)) = (_Float16)xc;
            }
        }
        // ---- stage 3 ----
        calc_bias(); fpi(5); epilogue();
        if (lane < 16) {
#pragma unroll
            for (int rr = 0; rr < 2; ++rr) {
                k3[rr] = accK[rr];
                float xc = fmaf(DT_F, k3[rr], xb[rr]);
                *(_Float16*)(W + xy_wr_off(rr, lane)) = (_Float16)xc;
            }
        }
        // ---- stage 4 ----
        calc_bias(); fpi(5); epilogue();
        if (lane < 16) {
#pragma unroll
            for (int rr = 0; rr < 2; ++rr) {
                k4[rr] = accK[rr];
                xb[rr] = fmaf(DT_F/6.0f,
                              k1[rr] + 2.0f*k2[rr] + 2.0f*k3[rr] + k4[rr], xb[rr]);
                *(_Float16*)(W + xy_wr_off(rr, lane)) = (_Float16)xb[rr];
            }
        }
    }
}

// ---- value baseline MLP + log_std broadcast (unchanged, passes) ----
__device__ __forceinline__ float fast_tanh(float a) {
    float e = __expf(2.0f * a);
    return 1.0f - 2.0f / (e + 1.0f);
}

__global__ __launch_bounds__(256) void mlp_kernel(
    const float* __restrict__ obs, const float* __restrict__ log_stds,
    const float* __restrict__ W1, const float* __restrict__ b1,
    const float* __restrict__ W2, const float* __restrict__ b2,
    const float* __restrict__ W3, const float* __restrict__ b3,
    float* __restrict__ out) {
    __shared__ float sW1[IN_D * H_D];
    __shared__ float sW2[H_D * H_D];
    __shared__ float sb1[H_D], sb2[H_D], sW3[H_D], sls[OUT_D];
    __shared__ float sb3;
    const int tid = threadIdx.x;
    for (int i = tid; i < IN_D * H_D; i += 256) sW1[i] = W1[i];
    for (int i = tid; i < H_D * H_D; i += 256) sW2[i] = W2[i];
    if (tid < H_D) { sb1[tid] = b1[tid]; sb2[tid] = b2[tid]; sW3[tid] = W3[tid]; }
    if (tid < OUT_D) sls[tid] = log_stds[tid];
    if (tid == 0) sb3 = b3[0];
    __syncthreads();

    const int bt = blockIdx.x * 256 + tid;
    if (bt >= B_TOT * T_STEPS) return;

    float o[IN_D];
#pragma unroll
    for (int i = 0; i < IN_D; ++i) o[i] = obs[bt * IN_D + i];

    float h1[H_D];
#pragma unroll
    for (int h = 0; h < H_D; ++h) {
        float a = sb1[h];
#pragma unroll
        for (int i = 0; i < IN_D; ++i) a = fmaf(o[i], sW1[i * H_D + h], a);
        h1[h] = fast_tanh(a);
    }
    float v = sb3;
#pragma unroll
    for (int h = 0; h < H_D; ++h) {
        float a = sb2[h];
#pragma unroll
        for (int i = 0; i < H_D; ++i) a = fmaf(h1[i], sW2[i * H_D + h], a);
        v = fmaf(fast_tanh(a), sW3[h], v);
    }

    float* o17 = out + bt * OUT_C;
#pragma unroll
    for (int q = 0; q < OUT_D; ++q) o17[OUT_D + q] = sls[q];
    o17[16] = v;
}

extern "C" void kernel_launch(void* const* d_in, const int* in_sizes, int n_in,
                              void* d_out, int out_size, void* d_ws, size_t ws_size,
                              hipStream_t stream) {
    const float* obs      = (const float*)d_in[0];
    const float* x0       = (const float*)d_in[1];
    const float* A_T      = (const float*)d_in[2];
    const float* Bw_T     = (const float*)d_in[3];
    const float* By_T     = (const float*)d_in[4];
    const float* Cv_T     = (const float*)d_in[5];
    const float* Dvw_T    = (const float*)d_in[6];
    const float* Dvy_T    = (const float*)d_in[7];
    const float* Cu_T     = (const float*)d_in[8];
    const float* Duw_T    = (const float*)d_in[9];
    const float* Duy_T    = (const float*)d_in[10];
    const float* log_stds = (const float*)d_in[11];
    const float* W1       = (const float*)d_in[12];
    const float* b1       = (const float*)d_in[13];
    const float* W2       = (const float*)d_in[14];
    const float* b2       = (const float*)d_in[15];
    const float* W3       = (const float*)d_in[16];
    const float* b3       = (const float*)d_in[17];
    float* out = (float*)d_out;

    rinn_mfma<<<dim3(B_TOT / 8), dim3(256), 0, stream>>>(
        obs, x0, A_T, Bw_T, By_T, Cv_T, Dvw_T, Dvy_T, Cu_T, Duw_T, Duy_T, out);
    mlp_kernel<<<dim3((B_TOT * T_STEPS + 255) / 256), dim3(256), 0, stream>>>(
        obs, log_stds, W1, b1, W2, b2, W3, b3, out);
}

// Round 5
// 1000.789 us; speedup vs baseline: 13.1500x; 1.5202x over previous
//
#include <hip/hip_runtime.h>

// DissipativeRINN — fp16 MFMA, register-resident w via k-permuted ds_bpermute.
// 512 blocks x 4 waves; 1 batch row per wave (2048 waves = 2 waves/SIMD).
// Dvw B-fragments resident in VGPRs (k-permuted: k = 16*slot + 4s+g so tanh
// packs feed A-fragments via 16 ds_bpermute — no LDS round trip, no barrier).
// bBias/bK/bU fragments in a block-shared LDS store (read once per RK4 stage).

typedef _Float16 f16x8 __attribute__((ext_vector_type(8)));
typedef float f32x4 __attribute__((ext_vector_type(4)));
typedef int i32x4 __attribute__((ext_vector_type(4)));

constexpr int B_TOT   = 2048;
constexpr int T_STEPS = 32;
constexpr int IN_D    = 16;
constexpr int ST_D    = 16;
constexpr int NL_D    = 128;
constexpr int OUT_D   = 8;
constexpr int H_D     = 64;
constexpr int OUT_C   = 17;
constexpr float DT_F  = 0.01f;
constexpr float SC    = 2.8853900817779268f;   // 2*log2(e): t = log2(e^{2a})

constexpr int FRAG_BYTES = 18 * 1024;          // 18 frags x [64 lanes x 16B]
// frag ids: 0-7 bBias[n], 8 bK0(xy), 9-12 bK w-chunks, 13 bU0(xy), 14-17 bU w-chunks

__global__ __launch_bounds__(256, 2) void rinn_mfma(
    const float* __restrict__ obs, const float* __restrict__ x0,
    const float* __restrict__ A_T, const float* __restrict__ Bw_T,
    const float* __restrict__ By_T, const float* __restrict__ Cv_T,
    const float* __restrict__ Dvw_T, const float* __restrict__ Dvy_T,
    const float* __restrict__ Cu_T, const float* __restrict__ Duw_T,
    const float* __restrict__ Duy_T, float* __restrict__ out)
{
    __shared__ __align__(16) char lds[FRAG_BYTES + 4 * 1024];
    const int tid  = threadIdx.x;
    const int wid  = tid >> 6;
    const int lane = tid & 63;
    const int g    = lane >> 4;
    const int c16  = lane & 15;
    const int row  = blockIdx.x * 4 + wid;     // one batch row per wave

    const f32x4 z4 = {0.f, 0.f, 0.f, 0.f};

    // ---- block-shared fragment store (built by wave 0) ----
    if (wid == 0) {
#pragma unroll
        for (int n = 0; n < 8; ++n) {          // bBias: [Cv;Dvy]*SC, K=32 std layout
            f16x8 h;
#pragma unroll
            for (int j = 0; j < 8; ++j) {
                int k = 8 * g + j;
                float v = (k < 16) ? Cv_T[k * NL_D + 16 * n + c16]
                                   : Dvy_T[(k - 16) * NL_D + 16 * n + c16];
                h[j] = (_Float16)(SC * v);
            }
            *(f32x4*)(lds + n * 1024 + lane * 16) = __builtin_bit_cast(f32x4, h);
        }
        {                                      // bK0/bU0: xy-part, std layout
            f16x8 hk, hu;
#pragma unroll
            for (int j = 0; j < 8; ++j) {
                int k = 8 * g + j;
                float vk = (k < 16) ? A_T[k * ST_D + c16] : By_T[(k - 16) * ST_D + c16];
                float vu = (c16 < OUT_D)
                    ? ((k < 16) ? Cu_T[k * OUT_D + c16] : Duy_T[(k - 16) * OUT_D + c16]) : 0.f;
                hk[j] = (_Float16)vk; hu[j] = (_Float16)vu;
            }
            *(f32x4*)(lds + 8 * 1024 + lane * 16)  = __builtin_bit_cast(f32x4, hk);
            *(f32x4*)(lds + 13 * 1024 + lane * 16) = __builtin_bit_cast(f32x4, hu);
        }
#pragma unroll
        for (int s = 0; s < 4; ++s) {          // w-chunks, PERMUTED k = 16j + 4s + g
            f16x8 hk, hu;
#pragma unroll
            for (int j = 0; j < 8; ++j) {
                int r0 = 16 * j + 4 * s + g;
                hk[j] = (_Float16)Bw_T[r0 * ST_D + c16];
                hu[j] = (_Float16)((c16 < OUT_D) ? Duw_T[r0 * OUT_D + c16] : 0.f);
            }
            *(f32x4*)(lds + (9 + s) * 1024 + lane * 16)  = __builtin_bit_cast(f32x4, hk);
            *(f32x4*)(lds + (14 + s) * 1024 + lane * 16) = __builtin_bit_cast(f32x4, hu);
        }
    }
    __syncthreads();   // only barrier in the kernel

    // ---- bD resident: B[s][n] slot j = SC * Dvw[16j+4s+g][16n+c16] ----
    f16x8 bD[4][8];
#pragma unroll
    for (int s = 0; s < 4; ++s)
#pragma unroll
        for (int n = 0; n < 8; ++n) {
            f16x8 h;
#pragma unroll
            for (int j = 0; j < 8; ++j)
                h[j] = (_Float16)(SC * Dvw_T[(16 * j + 4 * s + g) * NL_D + 16 * n + c16]);
            bD[s][n] = h;
        }

    // ---- per-wave xy tile [16][32] f16, row-major 64B/row (rows 1-15 zero) ----
    char* XY = lds + FRAG_BYTES + wid * 1024;
    *(f32x4*)(XY + lane * 16) = z4;
    float xb = 0.f;
    if (lane < 16) {
        xb = x0[row * ST_D + lane];
        *(_Float16*)(XY + 2 * lane) = (_Float16)xb;
    }

    const int bidx = 4 * g;                    // bpermute byte index base: src lane 4s+g

    auto ld_frag = [&](int f) -> f16x8 {
        return __builtin_bit_cast(f16x8, *(const f32x4*)(lds + f * 1024 + lane * 16));
    };
    auto ld_xy = [&]() -> f16x8 {
        return __builtin_bit_cast(f16x8, *(const f32x4*)(XY + c16 * 64 + g * 16));
    };

    int p0 = 0, p1 = 0, p2 = 0, p3 = 0;        // w packs: lane c holds w[16n+c] pairs
    f32x4 biasAcc[8];

    auto calc_bias = [&]() {
        f16x8 aXY = ld_xy();
#pragma unroll
        for (int n = 0; n < 8; ++n)
            biasAcc[n] = __builtin_amdgcn_mfma_f32_16x16x32_f16(aXY, ld_frag(n), z4, 0, 0, 0);
    };

#define GATHER(a, s)                                                      \
    {                                                                     \
        i32x4 q;                                                          \
        q[0] = __builtin_amdgcn_ds_bpermute(bidx + 16 * (s), p0);         \
        q[1] = __builtin_amdgcn_ds_bpermute(bidx + 16 * (s), p1);         \
        q[2] = __builtin_amdgcn_ds_bpermute(bidx + 16 * (s), p2);         \
        q[3] = __builtin_amdgcn_ds_bpermute(bidx + 16 * (s), p3);         \
        a = __builtin_bit_cast(f16x8, q);                                 \
    }

    auto fpi = [&](int niter) {
#pragma unroll 1
        for (int it = 0; it < niter; ++it) {
            f16x8 a0, a1, a2, a3;
            GATHER(a0, 0) GATHER(a1, 1) GATHER(a2, 2) GATHER(a3, 3)
            float v[8];
#pragma unroll
            for (int n = 0; n < 8; ++n) {
                f32x4 t = __builtin_amdgcn_mfma_f32_16x16x32_f16(a0, bD[0][n], biasAcc[n], 0, 0, 0);
                t = __builtin_amdgcn_mfma_f32_16x16x32_f16(a1, bD[1][n], t, 0, 0, 0);
                t = __builtin_amdgcn_mfma_f32_16x16x32_f16(a2, bD[2][n], t, 0, 0, 0);
                t = __builtin_amdgcn_mfma_f32_16x16x32_f16(a3, bD[3][n], t, 0, 0, 0);
                float e = __builtin_amdgcn_exp2f(t[0]);          // e^{2a}
                v[n] = fmaf(-2.0f, __builtin_amdgcn_rcpf(1.0f + e), 1.0f);
            }
            p0 = __builtin_bit_cast(int, __builtin_amdgcn_cvt_pkrtz(v[0], v[1]));
            p1 = __builtin_bit_cast(int, __builtin_amdgcn_cvt_pkrtz(v[2], v[3]));
            p2 = __builtin_bit_cast(int, __builtin_amdgcn_cvt_pkrtz(v[4], v[5]));
            p3 = __builtin_bit_cast(int, __builtin_amdgcn_cvt_pkrtz(v[6], v[7]));
        }
    };

#pragma unroll 1
    for (int t = 0; t < T_STEPS; ++t) {
        p0 = p1 = p2 = p3 = 0;                 // w_init = 0
        if (lane < 16) {
            float yv = obs[(row * T_STEPS + t) * IN_D + lane];
            *(_Float16*)(XY + 32 + 2 * lane) = (_Float16)yv;
        }
        float k1 = 0.f, k2 = 0.f, k3 = 0.f, k4 = 0.f;

        // ---- stage 1: 30 iters from 0; emit u and k1 ----
        calc_bias();
        fpi(30);
        {
            f16x8 a0, a1, a2, a3;
            GATHER(a0, 0) GATHER(a1, 1) GATHER(a2, 2) GATHER(a3, 3)
            f16x8 aXY = ld_xy();
            f32x4 accK = __builtin_amdgcn_mfma_f32_16x16x32_f16(aXY, ld_frag(8), z4, 0, 0, 0);
            accK = __builtin_amdgcn_mfma_f32_16x16x32_f16(a0, ld_frag(9),  accK, 0, 0, 0);
            accK = __builtin_amdgcn_mfma_f32_16x16x32_f16(a1, ld_frag(10), accK, 0, 0, 0);
            accK = __builtin_amdgcn_mfma_f32_16x16x32_f16(a2, ld_frag(11), accK, 0, 0, 0);
            accK = __builtin_amdgcn_mfma_f32_16x16x32_f16(a3, ld_frag(12), accK, 0, 0, 0);
            f32x4 accU = __builtin_amdgcn_mfma_f32_16x16x32_f16(aXY, ld_frag(13), z4, 0, 0, 0);
            accU = __builtin_amdgcn_mfma_f32_16x16x32_f16(a0, ld_frag(14), accU, 0, 0, 0);
            accU = __builtin_amdgcn_mfma_f32_16x16x32_f16(a1, ld_frag(15), accU, 0, 0, 0);
            accU = __builtin_amdgcn_mfma_f32_16x16x32_f16(a2, ld_frag(16), accU, 0, 0, 0);
            accU = __builtin_amdgcn_mfma_f32_16x16x32_f16(a3, ld_frag(17), accU, 0, 0, 0);
            if (lane < OUT_D) out[(row * T_STEPS + t) * OUT_C + lane] = accU[0];
            if (lane < 16) {
                k1 = accK[0];
                *(_Float16*)(XY + 2 * lane) = (_Float16)fmaf(0.5f * DT_F, k1, xb);
            }
        }
        // ---- stages 2-4: 5 iters each (warm start), k only ----
#pragma unroll 1
        for (int st = 1; st < 4; ++st) {
            calc_bias();
            fpi(5);
            f16x8 a0, a1, a2, a3;
            GATHER(a0, 0) GATHER(a1, 1) GATHER(a2, 2) GATHER(a3, 3)
            f16x8 aXY = ld_xy();
            f32x4 accK = __builtin_amdgcn_mfma_f32_16x16x32_f16(aXY, ld_frag(8), z4, 0, 0, 0);
            accK = __builtin_amdgcn_mfma_f32_16x16x32_f16(a0, ld_frag(9),  accK, 0, 0, 0);
            accK = __builtin_amdgcn_mfma_f32_16x16x32_f16(a1, ld_frag(10), accK, 0, 0, 0);
            accK = __builtin_amdgcn_mfma_f32_16x16x32_f16(a2, ld_frag(11), accK, 0, 0, 0);
            accK = __builtin_amdgcn_mfma_f32_16x16x32_f16(a3, ld_frag(12), accK, 0, 0, 0);
            if (lane < 16) {
                if (st == 1) {
                    k2 = accK[0];
                    *(_Float16*)(XY + 2 * lane) = (_Float16)fmaf(0.5f * DT_F, k2, xb);
                } else if (st == 2) {
                    k3 = accK[0];
                    *(_Float16*)(XY + 2 * lane) = (_Float16)fmaf(DT_F, k3, xb);
                } else {
                    k4 = accK[0];
                    xb = fmaf(DT_F / 6.0f, k1 + 2.0f * k2 + 2.0f * k3 + k4, xb);
                    *(_Float16*)(XY + 2 * lane) = (_Float16)xb;
                }
            }
        }
    }
}

// ---- value baseline MLP + log_std broadcast (unchanged) ----
__device__ __forceinline__ float fast_tanh(float a) {
    float e = __expf(2.0f * a);
    return 1.0f - 2.0f / (e + 1.0f);
}

__global__ __launch_bounds__(256) void mlp_kernel(
    const float* __restrict__ obs, const float* __restrict__ log_stds,
    const float* __restrict__ W1, const float* __restrict__ b1,
    const float* __restrict__ W2, const float* __restrict__ b2,
    const float* __restrict__ W3, const float* __restrict__ b3,
    float* __restrict__ out) {
    __shared__ float sW1[IN_D * H_D];
    __shared__ float sW2[H_D * H_D];
    __shared__ float sb1[H_D], sb2[H_D], sW3[H_D], sls[OUT_D];
    __shared__ float sb3;
    const int tid = threadIdx.x;
    for (int i = tid; i < IN_D * H_D; i += 256) sW1[i] = W1[i];
    for (int i = tid; i < H_D * H_D; i += 256) sW2[i] = W2[i];
    if (tid < H_D) { sb1[tid] = b1[tid]; sb2[tid] = b2[tid]; sW3[tid] = W3[tid]; }
    if (tid < OUT_D) sls[tid] = log_stds[tid];
    if (tid == 0) sb3 = b3[0];
    __syncthreads();

    const int bt = blockIdx.x * 256 + tid;
    if (bt >= B_TOT * T_STEPS) return;

    float o[IN_D];
#pragma unroll
    for (int i = 0; i < IN_D; ++i) o[i] = obs[bt * IN_D + i];

    float h1[H_D];
#pragma unroll
    for (int h = 0; h < H_D; ++h) {
        float a = sb1[h];
#pragma unroll
        for (int i = 0; i < IN_D; ++i) a = fmaf(o[i], sW1[i * H_D + h], a);
        h1[h] = fast_tanh(a);
    }
    float v = sb3;
#pragma unroll
    for (int h = 0; h < H_D; ++h) {
        float a = sb2[h];
#pragma unroll
        for (int i = 0; i < H_D; ++i) a = fmaf(h1[i], sW2[i * H_D + h], a);
        v = fmaf(fast_tanh(a), sW3[h], v);
    }

    float* o17 = out + bt * OUT_C;
#pragma unroll
    for (int q = 0; q < OUT_D; ++q) o17[OUT_D + q] = sls[q];
    o17[16] = v;
}

extern "C" void kernel_launch(void* const* d_in, const int* in_sizes, int n_in,
                              void* d_out, int out_size, void* d_ws, size_t ws_size,
                              hipStream_t stream) {
    const float* obs      = (const float*)d_in[0];
    const float* x0       = (const float*)d_in[1];
    const float* A_T      = (const float*)d_in[2];
    const float* Bw_T     = (const float*)d_in[3];
    const float* By_T     = (const float*)d_in[4];
    const float* Cv_T     = (const float*)d_in[5];
    const float* Dvw_T    = (const float*)d_in[6];
    const float* Dvy_T    = (const float*)d_in[7];
    const float* Cu_T     = (const float*)d_in[8];
    const float* Duw_T    = (const float*)d_in[9];
    const float* Duy_T    = (const float*)d_in[10];
    const float* log_stds = (const float*)d_in[11];
    const float* W1       = (const float*)d_in[12];
    const float* b1       = (const float*)d_in[13];
    const float* W2       = (const float*)d_in[14];
    const float* b2       = (const float*)d_in[15];
    const float* W3       = (const float*)d_in[16];
    const float* b3       = (const float*)d_in[17];
    float* out = (float*)d_out;

    rinn_mfma<<<dim3(B_TOT / 4), dim3(256), 0, stream>>>(
        obs, x0, A_T, Bw_T, By_T, Cv_T, Dvw_T, Dvy_T, Cu_T, Duw_T, Duy_T, out);
    mlp_kernel<<<dim3((B_TOT * T_STEPS + 255) / 256), dim3(256), 0, stream>>>(
        obs, log_stds, W1, b1, W2, b2, W3, b3, out);
}

// Round 6
// 782.932 us; speedup vs baseline: 16.8091x; 1.2783x over previous
//
#include <hip/hip_runtime.h>

// DissipativeRINN — fp16 MFMA, 2 batch rows per wave, register-resident w.
// 256 blocks x 4 waves; rows (2*wid_global, +1) in M-rows 0,1 of a 16x16 tile.
// Dvw B-fragments resident in VGPRs (k-permuted: k = 16*slot + 4s+g so tanh
// packs feed A-fragments via ds_bpermute — no LDS round trip, no barrier).
// Row-1 packs are relocated to lanes 16-31 (4 bpermute + 4 cndmask) so the
// same 16-bpermute gather serves both rows. 1 wave/SIMD, 256-VGPR budget.

typedef _Float16 f16x8 __attribute__((ext_vector_type(8)));
typedef float f32x4 __attribute__((ext_vector_type(4)));
typedef int i32x4 __attribute__((ext_vector_type(4)));

constexpr int B_TOT   = 2048;
constexpr int T_STEPS = 32;
constexpr int IN_D    = 16;
constexpr int ST_D    = 16;
constexpr int NL_D    = 128;
constexpr int OUT_D   = 8;
constexpr int H_D     = 64;
constexpr int OUT_C   = 17;
constexpr float DT_F  = 0.01f;
constexpr float SC    = 2.8853900817779268f;   // 2*log2(e): t = log2(e^{2a})

constexpr int FRAG_BYTES = 18 * 1024;          // 18 frags x [64 lanes x 16B]
// frag ids: 0-7 bBias[n], 8 bK0(xy), 9-12 bK w-chunks, 13 bU0(xy), 14-17 bU w-chunks

__global__ __launch_bounds__(256, 1) void rinn_mfma(
    const float* __restrict__ obs, const float* __restrict__ x0,
    const float* __restrict__ A_T, const float* __restrict__ Bw_T,
    const float* __restrict__ By_T, const float* __restrict__ Cv_T,
    const float* __restrict__ Dvw_T, const float* __restrict__ Dvy_T,
    const float* __restrict__ Cu_T, const float* __restrict__ Duw_T,
    const float* __restrict__ Duy_T, float* __restrict__ out)
{
    __shared__ __align__(16) char lds[FRAG_BYTES + 4 * 1024];
    const int tid  = threadIdx.x;
    const int wid  = tid >> 6;
    const int lane = tid & 63;
    const int g    = lane >> 4;
    const int c16  = lane & 15;
    const int b0   = (blockIdx.x * 4 + wid) * 2;   // two batch rows per wave

    const f32x4 z4 = {0.f, 0.f, 0.f, 0.f};

    // ---- block-shared fragment store (built by wave 0) ----
    if (wid == 0) {
#pragma unroll
        for (int n = 0; n < 8; ++n) {          // bBias: [Cv;Dvy]*SC, K=32 std layout
            f16x8 h;
#pragma unroll
            for (int j = 0; j < 8; ++j) {
                int k = 8 * g + j;
                float v = (k < 16) ? Cv_T[k * NL_D + 16 * n + c16]
                                   : Dvy_T[(k - 16) * NL_D + 16 * n + c16];
                h[j] = (_Float16)(SC * v);
            }
            *(f32x4*)(lds + n * 1024 + lane * 16) = __builtin_bit_cast(f32x4, h);
        }
        {                                      // bK0/bU0: xy-part, std layout
            f16x8 hk, hu;
#pragma unroll
            for (int j = 0; j < 8; ++j) {
                int k = 8 * g + j;
                float vk = (k < 16) ? A_T[k * ST_D + c16] : By_T[(k - 16) * ST_D + c16];
                float vu = (c16 < OUT_D)
                    ? ((k < 16) ? Cu_T[k * OUT_D + c16] : Duy_T[(k - 16) * OUT_D + c16]) : 0.f;
                hk[j] = (_Float16)vk; hu[j] = (_Float16)vu;
            }
            *(f32x4*)(lds + 8 * 1024 + lane * 16)  = __builtin_bit_cast(f32x4, hk);
            *(f32x4*)(lds + 13 * 1024 + lane * 16) = __builtin_bit_cast(f32x4, hu);
        }
#pragma unroll
        for (int s = 0; s < 4; ++s) {          // w-chunks, PERMUTED k = 16j + 4s + g
            f16x8 hk, hu;
#pragma unroll
            for (int j = 0; j < 8; ++j) {
                int r0 = 16 * j + 4 * s + g;
                hk[j] = (_Float16)Bw_T[r0 * ST_D + c16];
                hu[j] = (_Float16)((c16 < OUT_D) ? Duw_T[r0 * OUT_D + c16] : 0.f);
            }
            *(f32x4*)(lds + (9 + s) * 1024 + lane * 16)  = __builtin_bit_cast(f32x4, hk);
            *(f32x4*)(lds + (14 + s) * 1024 + lane * 16) = __builtin_bit_cast(f32x4, hu);
        }
    }
    __syncthreads();   // only barrier in the kernel

    // ---- bD resident: B[s][n] slot j = SC * Dvw[16j+4s+g][16n+c16] ----
    f16x8 bD[4][8];
#pragma unroll
    for (int s = 0; s < 4; ++s)
#pragma unroll
        for (int n = 0; n < 8; ++n) {
            f16x8 h;
#pragma unroll
            for (int j = 0; j < 8; ++j)
                h[j] = (_Float16)(SC * Dvw_T[(16 * j + 4 * s + g) * NL_D + 16 * n + c16]);
            bD[s][n] = h;
        }

    // ---- per-wave xy tile [16][32] f16, row-major 64B/row (rows 2-15 zero) ----
    char* XY = lds + FRAG_BYTES + wid * 1024;
    *(f32x4*)(XY + lane * 16) = z4;
    float xb[2] = {0.f, 0.f};
    if (lane < 16) {
        xb[0] = x0[b0 * ST_D + lane];
        xb[1] = x0[(b0 + 1) * ST_D + lane];
        *(_Float16*)(XY + 2 * lane)      = (_Float16)xb[0];
        *(_Float16*)(XY + 64 + 2 * lane) = (_Float16)xb[1];
    }

    // gather base: A-row (l&15): row0 packs live in lanes 0-15, row1 in 16-31.
    const int gbase = 4 * g + ((c16 == 1) ? 64 : 0);
    const int rloc  = 4 * c16;                 // relocate idx: lane 16+c reads lane c
    const bool isg1 = (g == 1);

    auto ld_frag = [&](int f) -> f16x8 {
        return __builtin_bit_cast(f16x8, *(const f32x4*)(lds + f * 1024 + lane * 16));
    };
    auto ld_xy = [&]() -> f16x8 {
        return __builtin_bit_cast(f16x8, *(const f32x4*)(XY + c16 * 64 + g * 16));
    };

    int p0 = 0, p1 = 0, p2 = 0, p3 = 0;   // lanes 0-15: row0 packs; 16-31: row1
    f32x4 biasAcc[8];

    auto calc_bias = [&]() {
        f16x8 aXY = ld_xy();
#pragma unroll
        for (int n = 0; n < 8; ++n)
            biasAcc[n] = __builtin_amdgcn_mfma_f32_16x16x32_f16(aXY, ld_frag(n), z4, 0, 0, 0);
    };

#define GATHER(a, s)                                                      \
    {                                                                     \
        i32x4 q;                                                          \
        q[0] = __builtin_amdgcn_ds_bpermute(gbase + 16 * (s), p0);        \
        q[1] = __builtin_amdgcn_ds_bpermute(gbase + 16 * (s), p1);        \
        q[2] = __builtin_amdgcn_ds_bpermute(gbase + 16 * (s), p2);        \
        q[3] = __builtin_amdgcn_ds_bpermute(gbase + 16 * (s), p3);        \
        a = __builtin_bit_cast(f16x8, q);                                 \
    }

    auto fpi = [&](int niter) {
#pragma unroll 1
        for (int it = 0; it < niter; ++it) {
            f16x8 a0, a1, a2, a3;
            GATHER(a0, 0) GATHER(a1, 1) GATHER(a2, 2) GATHER(a3, 3)
            float v0[8], v1[8];
#pragma unroll
            for (int n = 0; n < 8; ++n) {
                f32x4 t = __builtin_amdgcn_mfma_f32_16x16x32_f16(a0, bD[0][n], biasAcc[n], 0, 0, 0);
                t = __builtin_amdgcn_mfma_f32_16x16x32_f16(a1, bD[1][n], t, 0, 0, 0);
                t = __builtin_amdgcn_mfma_f32_16x16x32_f16(a2, bD[2][n], t, 0, 0, 0);
                t = __builtin_amdgcn_mfma_f32_16x16x32_f16(a3, bD[3][n], t, 0, 0, 0);
                float e0 = __builtin_amdgcn_exp2f(t[0]);         // e^{2a} row0
                float e1 = __builtin_amdgcn_exp2f(t[1]);         // e^{2a} row1
                v0[n] = fmaf(-2.0f, __builtin_amdgcn_rcpf(1.0f + e0), 1.0f);
                v1[n] = fmaf(-2.0f, __builtin_amdgcn_rcpf(1.0f + e1), 1.0f);
            }
            p0 = __builtin_bit_cast(int, __builtin_amdgcn_cvt_pkrtz(v0[0], v0[1]));
            p1 = __builtin_bit_cast(int, __builtin_amdgcn_cvt_pkrtz(v0[2], v0[3]));
            p2 = __builtin_bit_cast(int, __builtin_amdgcn_cvt_pkrtz(v0[4], v0[5]));
            p3 = __builtin_bit_cast(int, __builtin_amdgcn_cvt_pkrtz(v0[6], v0[7]));
            int r0 = __builtin_bit_cast(int, __builtin_amdgcn_cvt_pkrtz(v1[0], v1[1]));
            int r1 = __builtin_bit_cast(int, __builtin_amdgcn_cvt_pkrtz(v1[2], v1[3]));
            int r2 = __builtin_bit_cast(int, __builtin_amdgcn_cvt_pkrtz(v1[4], v1[5]));
            int r3 = __builtin_bit_cast(int, __builtin_amdgcn_cvt_pkrtz(v1[6], v1[7]));
            // relocate row1 packs into lanes 16-31
            int m0 = __builtin_amdgcn_ds_bpermute(rloc, r0);
            int m1 = __builtin_amdgcn_ds_bpermute(rloc, r1);
            int m2 = __builtin_amdgcn_ds_bpermute(rloc, r2);
            int m3 = __builtin_amdgcn_ds_bpermute(rloc, r3);
            p0 = isg1 ? m0 : p0;
            p1 = isg1 ? m1 : p1;
            p2 = isg1 ? m2 : p2;
            p3 = isg1 ? m3 : p3;
        }
    };

#pragma unroll 1
    for (int t = 0; t < T_STEPS; ++t) {
        p0 = p1 = p2 = p3 = 0;                 // w_init = 0 (both rows)
        if (lane < 16) {
            *(_Float16*)(XY + 32 + 2 * lane) =
                (_Float16)obs[(b0 * T_STEPS + t) * IN_D + lane];
            *(_Float16*)(XY + 64 + 32 + 2 * lane) =
                (_Float16)obs[((b0 + 1) * T_STEPS + t) * IN_D + lane];
        }
        float k1[2], k2[2], k3[2], k4[2];

        // ---- stage 1: 30 iters from 0; emit u and k1 ----
        calc_bias();
        fpi(30);
        {
            f16x8 a0, a1, a2, a3;
            GATHER(a0, 0) GATHER(a1, 1) GATHER(a2, 2) GATHER(a3, 3)
            f16x8 aXY = ld_xy();
            f32x4 accK = __builtin_amdgcn_mfma_f32_16x16x32_f16(aXY, ld_frag(8), z4, 0, 0, 0);
            accK = __builtin_amdgcn_mfma_f32_16x16x32_f16(a0, ld_frag(9),  accK, 0, 0, 0);
            accK = __builtin_amdgcn_mfma_f32_16x16x32_f16(a1, ld_frag(10), accK, 0, 0, 0);
            accK = __builtin_amdgcn_mfma_f32_16x16x32_f16(a2, ld_frag(11), accK, 0, 0, 0);
            accK = __builtin_amdgcn_mfma_f32_16x16x32_f16(a3, ld_frag(12), accK, 0, 0, 0);
            f32x4 accU = __builtin_amdgcn_mfma_f32_16x16x32_f16(aXY, ld_frag(13), z4, 0, 0, 0);
            accU = __builtin_amdgcn_mfma_f32_16x16x32_f16(a0, ld_frag(14), accU, 0, 0, 0);
            accU = __builtin_amdgcn_mfma_f32_16x16x32_f16(a1, ld_frag(15), accU, 0, 0, 0);
            accU = __builtin_amdgcn_mfma_f32_16x16x32_f16(a2, ld_frag(16), accU, 0, 0, 0);
            accU = __builtin_amdgcn_mfma_f32_16x16x32_f16(a3, ld_frag(17), accU, 0, 0, 0);
            if (lane < OUT_D) {
                out[(b0 * T_STEPS + t) * OUT_C + lane]       = accU[0];
                out[((b0 + 1) * T_STEPS + t) * OUT_C + lane] = accU[1];
            }
            if (lane < 16) {
                k1[0] = accK[0]; k1[1] = accK[1];
                *(_Float16*)(XY + 2 * lane)      = (_Float16)fmaf(0.5f * DT_F, k1[0], xb[0]);
                *(_Float16*)(XY + 64 + 2 * lane) = (_Float16)fmaf(0.5f * DT_F, k1[1], xb[1]);
            }
        }
        // ---- stages 2-4: 5 iters each (warm start), k only ----
#pragma unroll 1
        for (int st = 1; st < 4; ++st) {
            calc_bias();
            fpi(5);
            f16x8 a0, a1, a2, a3;
            GATHER(a0, 0) GATHER(a1, 1) GATHER(a2, 2) GATHER(a3, 3)
            f16x8 aXY = ld_xy();
            f32x4 accK = __builtin_amdgcn_mfma_f32_16x16x32_f16(aXY, ld_frag(8), z4, 0, 0, 0);
            accK = __builtin_amdgcn_mfma_f32_16x16x32_f16(a0, ld_frag(9),  accK, 0, 0, 0);
            accK = __builtin_amdgcn_mfma_f32_16x16x32_f16(a1, ld_frag(10), accK, 0, 0, 0);
            accK = __builtin_amdgcn_mfma_f32_16x16x32_f16(a2, ld_frag(11), accK, 0, 0, 0);
            accK = __builtin_amdgcn_mfma_f32_16x16x32_f16(a3, ld_frag(12), accK, 0, 0, 0);
            if (lane < 16) {
                if (st == 1) {
                    k2[0] = accK[0]; k2[1] = accK[1];
                    *(_Float16*)(XY + 2 * lane)      = (_Float16)fmaf(0.5f * DT_F, k2[0], xb[0]);
                    *(_Float16*)(XY + 64 + 2 * lane) = (_Float16)fmaf(0.5f * DT_F, k2[1], xb[1]);
                } else if (st == 2) {
                    k3[0] = accK[0]; k3[1] = accK[1];
                    *(_Float16*)(XY + 2 * lane)      = (_Float16)fmaf(DT_F, k3[0], xb[0]);
                    *(_Float16*)(XY + 64 + 2 * lane) = (_Float16)fmaf(DT_F, k3[1], xb[1]);
                } else {
                    k4[0] = accK[0]; k4[1] = accK[1];
                    xb[0] = fmaf(DT_F / 6.0f, k1[0] + 2.0f * k2[0] + 2.0f * k3[0] + k4[0], xb[0]);
                    xb[1] = fmaf(DT_F / 6.0f, k1[1] + 2.0f * k2[1] + 2.0f * k3[1] + k4[1], xb[1]);
                    *(_Float16*)(XY + 2 * lane)      = (_Float16)xb[0];
                    *(_Float16*)(XY + 64 + 2 * lane) = (_Float16)xb[1];
                }
            }
        }
    }
}

// ---- value baseline MLP + log_std broadcast (unchanged) ----
__device__ __forceinline__ float fast_tanh(float a) {
    float e = __expf(2.0f * a);
    return 1.0f - 2.0f / (e + 1.0f);
}

__global__ __launch_bounds__(256) void mlp_kernel(
    const float* __restrict__ obs, const float* __restrict__ log_stds,
    const float* __restrict__ W1, const float* __restrict__ b1,
    const float* __restrict__ W2, const float* __restrict__ b2,
    const float* __restrict__ W3, const float* __restrict__ b3,
    float* __restrict__ out) {
    __shared__ float sW1[IN_D * H_D];
    __shared__ float sW2[H_D * H_D];
    __shared__ float sb1[H_D], sb2[H_D], sW3[H_D], sls[OUT_D];
    __shared__ float sb3;
    const int tid = threadIdx.x;
    for (int i = tid; i < IN_D * H_D; i += 256) sW1[i] = W1[i];
    for (int i = tid; i < H_D * H_D; i += 256) sW2[i] = W2[i];
    if (tid < H_D) { sb1[tid] = b1[tid]; sb2[tid] = b2[tid]; sW3[tid] = W3[tid]; }
    if (tid < OUT_D) sls[tid] = log_stds[tid];
    if (tid == 0) sb3 = b3[0];
    __syncthreads();

    const int bt = blockIdx.x * 256 + tid;
    if (bt >= B_TOT * T_STEPS) return;

    float o[IN_D];
#pragma unroll
    for (int i = 0; i < IN_D; ++i) o[i] = obs[bt * IN_D + i];

    float h1[H_D];
#pragma unroll
    for (int h = 0; h < H_D; ++h) {
        float a = sb1[h];
#pragma unroll
        for (int i = 0; i < IN_D; ++i) a = fmaf(o[i], sW1[i * H_D + h], a);
        h1[h] = fast_tanh(a);
    }
    float v = sb3;
#pragma unroll
    for (int h = 0; h < H_D; ++h) {
        float a = sb2[h];
#pragma unroll
        for (int i = 0; i < H_D; ++i) a = fmaf(h1[i], sW2[i * H_D + h], a);
        v = fmaf(fast_tanh(a), sW3[h], v);
    }

    float* o17 = out + bt * OUT_C;
#pragma unroll
    for (int q = 0; q < OUT_D; ++q) o17[OUT_D + q] = sls[q];
    o17[16] = v;
}

extern "C" void kernel_launch(void* const* d_in, const int* in_sizes, int n_in,
                              void* d_out, int out_size, void* d_ws, size_t ws_size,
                              hipStream_t stream) {
    const float* obs      = (const float*)d_in[0];
    const float* x0       = (const float*)d_in[1];
    const float* A_T      = (const float*)d_in[2];
    const float* Bw_T     = (const float*)d_in[3];
    const float* By_T     = (const float*)d_in[4];
    const float* Cv_T     = (const float*)d_in[5];
    const float* Dvw_T    = (const float*)d_in[6];
    const float* Dvy_T    = (const float*)d_in[7];
    const float* Cu_T     = (const float*)d_in[8];
    const float* Duw_T    = (const float*)d_in[9];
    const float* Duy_T    = (const float*)d_in[10];
    const float* log_stds = (const float*)d_in[11];
    const float* W1       = (const float*)d_in[12];
    const float* b1       = (const float*)d_in[13];
    const float* W2       = (const float*)d_in[14];
    const float* b2       = (const float*)d_in[15];
    const float* W3       = (const float*)d_in[16];
    const float* b3       = (const float*)d_in[17];
    float* out = (float*)d_out;

    rinn_mfma<<<dim3(B_TOT / 8), dim3(256), 0, stream>>>(
        obs, x0, A_T, Bw_T, By_T, Cv_T, Dvw_T, Dvy_T, Cu_T, Duw_T, Duy_T, out);
    mlp_kernel<<<dim3((B_TOT * T_STEPS + 255) / 256), dim3(256), 0, stream>>>(
        obs, log_stds, W1, b1, W2, b2, W3, b3, out);
}

// Round 7
// 539.131 us; speedup vs baseline: 24.4103x; 1.4522x over previous
//
#include <hip/hip_runtime.h>

// DissipativeRINN — fp16 MFMA, block-cooperative K-reduction.
// 256 blocks x 8 waves (512 thr); block = 8 batch rows (M-rows 0-7 of a 16-tile).
// Wave w owns N-tile w (w-cols 16w..16w+15): 4 MFMA per fixed-point iteration.
// w matrix exchanged via double-buffered XOR-swizzled LDS tile [16][128] f16;
// one __syncthreads per iteration. Epilogue k/u = single 16x16 tiles (K=160)
// on waves 0/1. Dvw/bias/K/U fragments resident in VGPRs.

typedef _Float16 f16x8 __attribute__((ext_vector_type(8)));
typedef float f32x4 __attribute__((ext_vector_type(4)));

constexpr int B_TOT   = 2048;
constexpr int T_STEPS = 32;
constexpr int IN_D    = 16;
constexpr int ST_D    = 16;
constexpr int NL_D    = 128;
constexpr int OUT_D   = 8;
constexpr int H_D     = 64;
constexpr int OUT_C   = 17;
constexpr float DT_F  = 0.01f;
constexpr float SC    = 2.8853900817779268f;   // 2*log2(e)

constexpr int RB      = 8;                     // batch rows per block
constexpr int WBUF_SZ = 4096;                  // [16 rows][128 k] f16
constexpr int XY_OFF  = 2 * WBUF_SZ;           // xy tile [16][32] f16 (1 KB)
constexpr int LDS_SZ  = XY_OFF + 1024;

__global__ __launch_bounds__(512, 1) void rinn_fpi(
    const float* __restrict__ obs, const float* __restrict__ x0,
    const float* __restrict__ A_T, const float* __restrict__ Bw_T,
    const float* __restrict__ By_T, const float* __restrict__ Cv_T,
    const float* __restrict__ Dvw_T, const float* __restrict__ Dvy_T,
    const float* __restrict__ Cu_T, const float* __restrict__ Duw_T,
    const float* __restrict__ Duy_T, float* __restrict__ out)
{
    __shared__ __align__(16) char lds[LDS_SZ];
    const int tid  = threadIdx.x;
    const int wid  = tid >> 6;                 // N-tile owned by this wave
    const int lane = tid & 63;
    const int g    = lane >> 4;
    const int c16  = lane & 15;
    const int b0   = blockIdx.x * RB;
    const int col  = 16 * wid + c16;           // this wave's w-column
    const f32x4 z4 = {0.f, 0.f, 0.f, 0.f};

    // ---- resident B fragments ----
    f16x8 bD[4];                               // Dvw k-chunks for N-tile wid (x SC)
#pragma unroll
    for (int s = 0; s < 4; ++s) {
        f16x8 h;
#pragma unroll
        for (int j = 0; j < 8; ++j)
            h[j] = (_Float16)(SC * Dvw_T[(s * 32 + g * 8 + j) * NL_D + col]);
        bD[s] = h;
    }
    f16x8 bBias;                               // [Cv;Dvy] K=32 (x SC)
    {
        f16x8 h;
#pragma unroll
        for (int j = 0; j < 8; ++j) {
            int k = g * 8 + j;
            float v = (k < 16) ? Cv_T[k * NL_D + col] : Dvy_T[(k - 16) * NL_D + col];
            h[j] = (_Float16)(SC * v);
        }
        bBias = h;
    }
    f16x8 bKU[5];                              // wave0: [A;By;Bw], wave1: [Cu;Duy;Duw]
    if (wid == 0) {
        f16x8 h;
#pragma unroll
        for (int j = 0; j < 8; ++j) {
            int k = g * 8 + j;
            h[j] = (_Float16)((k < 16) ? A_T[k * ST_D + c16] : By_T[(k - 16) * ST_D + c16]);
        }
        bKU[0] = h;
#pragma unroll
        for (int s = 0; s < 4; ++s) {
            f16x8 h2;
#pragma unroll
            for (int j = 0; j < 8; ++j)
                h2[j] = (_Float16)Bw_T[(s * 32 + g * 8 + j) * ST_D + c16];
            bKU[1 + s] = h2;
        }
    } else if (wid == 1) {
        f16x8 h;
#pragma unroll
        for (int j = 0; j < 8; ++j) {
            int k = g * 8 + j;
            float v = (c16 < OUT_D)
                ? ((k < 16) ? Cu_T[k * OUT_D + c16] : Duy_T[(k - 16) * OUT_D + c16]) : 0.f;
            h[j] = (_Float16)v;
        }
        bKU[0] = h;
#pragma unroll
        for (int s = 0; s < 4; ++s) {
            f16x8 h2;
#pragma unroll
            for (int j = 0; j < 8; ++j)
                h2[j] = (_Float16)((c16 < OUT_D) ? Duw_T[(s * 32 + g * 8 + j) * OUT_D + c16] : 0.f);
            bKU[1 + s] = h2;
        }
    }

    // ---- zero all LDS (pad rows 8-15 must stay zero forever) ----
    for (int off = tid * 16; off < LDS_SZ; off += 512 * 16)
        *(f32x4*)(lds + off) = z4;
    __syncthreads();

    // ---- x state: wave 0 lanes g<2 hold rows 4g+j, col c16 ----
    f32x4 xb = z4, k1 = z4, k2 = z4, k3 = z4, k4 = z4;
    if (wid == 0 && g < 2) {
#pragma unroll
        for (int j = 0; j < 4; ++j) {
            int row = 4 * g + j;
            xb[j] = x0[(b0 + row) * ST_D + c16];
            *(_Float16*)(lds + XY_OFF + row * 64 + ((2 * c16) ^ ((row & 3) << 4))) =
                (_Float16)xb[j];
        }
    }

    auto ld_xy = [&]() -> f16x8 {
        return __builtin_bit_cast(f16x8,
            *(const f32x4*)(lds + XY_OFF + c16 * 64 + ((g * 16) ^ ((c16 & 3) << 4))));
    };
    auto ldA = [&](int buf, int s) -> f16x8 {
        return __builtin_bit_cast(f16x8,
            *(const f32x4*)(lds + buf * WBUF_SZ + c16 * 256 +
                            ((s * 64 + g * 16) ^ ((c16 & 7) << 4))));
    };

    int cur = 0;

#pragma unroll 1
    for (int t = 0; t < T_STEPS; ++t) {
        // w_init = 0: zero rows 0-7 of w[cur] (2 KB, 4B/thread)
        *(int*)(lds + cur * WBUF_SZ + tid * 4) = 0;
        // y rows 0-7 for this step (wave 2)
        if (wid == 2 && g < 2) {
#pragma unroll
            for (int j = 0; j < 4; ++j) {
                int row = 4 * g + j;
                float yv = obs[((b0 + row) * T_STEPS + t) * IN_D + c16];
                *(_Float16*)(lds + XY_OFF + row * 64 + ((32 + 2 * c16) ^ ((row & 3) << 4))) =
                    (_Float16)yv;
            }
        }
        __syncthreads();

#pragma unroll 1
        for (int st = 0; st < 4; ++st) {
            // bias for this stage's x
            f32x4 biasAcc;
            {
                f16x8 aXY = ld_xy();
                biasAcc = __builtin_amdgcn_mfma_f32_16x16x32_f16(aXY, bBias, z4, 0, 0, 0);
            }
            const int niter = st ? 5 : 30;
#pragma unroll 1
            for (int it = 0; it < niter; ++it) {
                f16x8 a0 = ldA(cur, 0), a1 = ldA(cur, 1), a2 = ldA(cur, 2), a3 = ldA(cur, 3);
                f32x4 tt = __builtin_amdgcn_mfma_f32_16x16x32_f16(a0, bD[0], biasAcc, 0, 0, 0);
                tt = __builtin_amdgcn_mfma_f32_16x16x32_f16(a1, bD[1], tt, 0, 0, 0);
                tt = __builtin_amdgcn_mfma_f32_16x16x32_f16(a2, bD[2], tt, 0, 0, 0);
                tt = __builtin_amdgcn_mfma_f32_16x16x32_f16(a3, bD[3], tt, 0, 0, 0);
                if (g < 2) {                   // rows 0-7 real; write w[nxt]
#pragma unroll
                    for (int j = 0; j < 4; ++j) {
                        float e = __builtin_amdgcn_exp2f(tt[j]);       // e^{2a}
                        float v = fmaf(-2.0f, __builtin_amdgcn_rcpf(1.0f + e), 1.0f);
                        int row = 4 * g + j;
                        *(_Float16*)(lds + (cur ^ 1) * WBUF_SZ + row * 256 +
                                     ((2 * col) ^ ((row & 7) << 4))) = (_Float16)v;
                    }
                }
                __syncthreads();
                cur ^= 1;
            }
            // ---- epilogue: k (wave 0) / u (wave 1), K=160 over [xy | w] ----
            f32x4 acc = z4;
            if (wid < 2) {
                f16x8 aXY = ld_xy();
                f16x8 a0 = ldA(cur, 0), a1 = ldA(cur, 1), a2 = ldA(cur, 2), a3 = ldA(cur, 3);
                acc = __builtin_amdgcn_mfma_f32_16x16x32_f16(aXY, bKU[0], z4, 0, 0, 0);
                acc = __builtin_amdgcn_mfma_f32_16x16x32_f16(a0, bKU[1], acc, 0, 0, 0);
                acc = __builtin_amdgcn_mfma_f32_16x16x32_f16(a1, bKU[2], acc, 0, 0, 0);
                acc = __builtin_amdgcn_mfma_f32_16x16x32_f16(a2, bKU[3], acc, 0, 0, 0);
                acc = __builtin_amdgcn_mfma_f32_16x16x32_f16(a3, bKU[4], acc, 0, 0, 0);
            }
            __syncthreads();                   // xy reads done before x update
            if (wid == 1 && st == 0 && c16 < OUT_D && g < 2) {
#pragma unroll
                for (int j = 0; j < 4; ++j)
                    out[((b0 + 4 * g + j) * T_STEPS + t) * OUT_C + c16] = acc[j];
            }
            if (wid == 0) {
                float xn[4];
                if (st == 0) {
                    k1 = acc;
#pragma unroll
                    for (int j = 0; j < 4; ++j) xn[j] = fmaf(0.5f * DT_F, k1[j], xb[j]);
                } else if (st == 1) {
                    k2 = acc;
#pragma unroll
                    for (int j = 0; j < 4; ++j) xn[j] = fmaf(0.5f * DT_F, k2[j], xb[j]);
                } else if (st == 2) {
                    k3 = acc;
#pragma unroll
                    for (int j = 0; j < 4; ++j) xn[j] = fmaf(DT_F, k3[j], xb[j]);
                } else {
                    k4 = acc;
#pragma unroll
                    for (int j = 0; j < 4; ++j) {
                        xb[j] = fmaf(DT_F / 6.0f,
                                     k1[j] + 2.0f * k2[j] + 2.0f * k3[j] + k4[j], xb[j]);
                        xn[j] = xb[j];
                    }
                }
                if (g < 2) {
#pragma unroll
                    for (int j = 0; j < 4; ++j) {
                        int row = 4 * g + j;
                        *(_Float16*)(lds + XY_OFF + row * 64 +
                                     ((2 * c16) ^ ((row & 3) << 4))) = (_Float16)xn[j];
                    }
                }
            }
            __syncthreads();                   // new x visible for next bias
        }
    }
}

// ---- value baseline MLP + log_std broadcast (unchanged) ----
__device__ __forceinline__ float fast_tanh(float a) {
    float e = __expf(2.0f * a);
    return 1.0f - 2.0f / (e + 1.0f);
}

__global__ __launch_bounds__(256) void mlp_kernel(
    const float* __restrict__ obs, const float* __restrict__ log_stds,
    const float* __restrict__ W1, const float* __restrict__ b1,
    const float* __restrict__ W2, const float* __restrict__ b2,
    const float* __restrict__ W3, const float* __restrict__ b3,
    float* __restrict__ out) {
    __shared__ float sW1[IN_D * H_D];
    __shared__ float sW2[H_D * H_D];
    __shared__ float sb1[H_D], sb2[H_D], sW3[H_D], sls[OUT_D];
    __shared__ float sb3;
    const int tid = threadIdx.x;
    for (int i = tid; i < IN_D * H_D; i += 256) sW1[i] = W1[i];
    for (int i = tid; i < H_D * H_D; i += 256) sW2[i] = W2[i];
    if (tid < H_D) { sb1[tid] = b1[tid]; sb2[tid] = b2[tid]; sW3[tid] = W3[tid]; }
    if (tid < OUT_D) sls[tid] = log_stds[tid];
    if (tid == 0) sb3 = b3[0];
    __syncthreads();

    const int bt = blockIdx.x * 256 + tid;
    if (bt >= B_TOT * T_STEPS) return;

    float o[IN_D];
#pragma unroll
    for (int i = 0; i < IN_D; ++i) o[i] = obs[bt * IN_D + i];

    float h1[H_D];
#pragma unroll
    for (int h = 0; h < H_D; ++h) {
        float a = sb1[h];
#pragma unroll
        for (int i = 0; i < IN_D; ++i) a = fmaf(o[i], sW1[i * H_D + h], a);
        h1[h] = fast_tanh(a);
    }
    float v = sb3;
#pragma unroll
    for (int h = 0; h < H_D; ++h) {
        float a = sb2[h];
#pragma unroll
        for (int i = 0; i < H_D; ++i) a = fmaf(h1[i], sW2[i * H_D + h], a);
        v = fmaf(fast_tanh(a), sW3[h], v);
    }

    float* o17 = out + bt * OUT_C;
#pragma unroll
    for (int q = 0; q < OUT_D; ++q) o17[OUT_D + q] = sls[q];
    o17[16] = v;
}

extern "C" void kernel_launch(void* const* d_in, const int* in_sizes, int n_in,
                              void* d_out, int out_size, void* d_ws, size_t ws_size,
                              hipStream_t stream) {
    const float* obs      = (const float*)d_in[0];
    const float* x0       = (const float*)d_in[1];
    const float* A_T      = (const float*)d_in[2];
    const float* Bw_T     = (const float*)d_in[3];
    const float* By_T     = (const float*)d_in[4];
    const float* Cv_T     = (const float*)d_in[5];
    const float* Dvw_T    = (const float*)d_in[6];
    const float* Dvy_T    = (const float*)d_in[7];
    const float* Cu_T     = (const float*)d_in[8];
    const float* Duw_T    = (const float*)d_in[9];
    const float* Duy_T    = (const float*)d_in[10];
    const float* log_stds = (const float*)d_in[11];
    const float* W1       = (const float*)d_in[12];
    const float* b1       = (const float*)d_in[13];
    const float* W2       = (const float*)d_in[14];
    const float* b2       = (const float*)d_in[15];
    const float* W3       = (const float*)d_in[16];
    const float* b3       = (const float*)d_in[17];
    float* out = (float*)d_out;

    rinn_fpi<<<dim3(B_TOT / RB), dim3(512), 0, stream>>>(
        obs, x0, A_T, Bw_T, By_T, Cv_T, Dvw_T, Dvy_T, Cu_T, Duw_T, Duy_T, out);
    mlp_kernel<<<dim3((B_TOT * T_STEPS + 255) / 256), dim3(256), 0, stream>>>(
        obs, log_stds, W1, b1, W2, b2, W3, b3, out);
}